// Round 1
// baseline (421.779 us; speedup 1.0000x reference)
//
#include <hip/hip_runtime.h>
#include <math.h>

#define DIMN 128
#define KXN  65
#define NBATCH 8
#define NOPT 125

// ---------------- Volume FFT pass 1: rfft over x, sign (-1)^k ----------------
// out layout: A_T[(z*65+k)*128 + y]
__global__ __launch_bounds__(128) void k_vol_fx(const float* __restrict__ vol,
                                                float2* __restrict__ outT){
  __shared__ float line[DIMN];
  __shared__ float2 tw[DIMN];
  int t = threadIdx.x;
  int zy = blockIdx.x;              // z*128 + y
  line[t] = vol[zy*DIMN + t];
  {
    float a = 6.283185307179586f * (float)t / 128.0f;
    float s, c; sincosf(a, &s, &c);
    tw[t] = make_float2(c, -s);     // e^{-2pi i t/128}
  }
  __syncthreads();
  if (t < KXN){
    float ar = 0.f, ai = 0.f;
    for (int x = 0; x < DIMN; ++x){
      float v = line[x];
      float2 w = tw[(t*x) & 127];
      ar += v*w.x; ai += v*w.y;
    }
    float sg = (t & 1) ? -1.f : 1.f;
    int z = zy >> 7, y = zy & 127;
    outT[(z*KXN + t)*DIMN + y] = make_float2(sg*ar, sg*ai);
  }
}

// ---------------- Volume FFT pass 2: fft over y, output-shifted j, sign (-1)^j
// in: A_T[(z*65+k)*128 + y]   out: B_T[(j*65+k)*128 + z]
__global__ __launch_bounds__(128) void k_vol_fy(const float2* __restrict__ inT,
                                                float2* __restrict__ outT){
  __shared__ float2 line[DIMN];
  __shared__ float2 tw[DIMN];
  int t = threadIdx.x;
  int bid = blockIdx.x;             // z*65 + k
  int z = bid / 65, k = bid - z*65;
  line[t] = inT[(z*KXN + k)*DIMN + t];
  {
    float a = 6.283185307179586f * (float)t / 128.0f;
    float s, c; sincosf(a, &s, &c);
    tw[t] = make_float2(c, -s);
  }
  __syncthreads();
  int f = (t + 64) & 127;           // DFT frequency for output index t
  float ar = 0.f, ai = 0.f;
  for (int y = 0; y < DIMN; ++y){
    float2 v = line[y];
    float2 w = tw[(f*y) & 127];
    ar += v.x*w.x - v.y*w.y;
    ai += v.x*w.y + v.y*w.x;
  }
  float sg = (t & 1) ? -1.f : 1.f;
  outT[(t*KXN + k)*DIMN + z] = make_float2(sg*ar, sg*ai);
}

// ---------------- Volume FFT pass 3: fft over z, output-shifted i, sign (-1)^i
// in: B_T[(j*65+k)*128 + z]   out: volF[(i*128+j)*65 + k]  (== reference vol_rfft)
__global__ __launch_bounds__(128) void k_vol_fz(const float2* __restrict__ inT,
                                                float2* __restrict__ volF){
  __shared__ float2 line[DIMN];
  __shared__ float2 tw[DIMN];
  int t = threadIdx.x;
  int bid = blockIdx.x;             // j*65 + k
  int j = bid / 65, k = bid - j*65;
  line[t] = inT[(j*KXN + k)*DIMN + t];
  {
    float a = 6.283185307179586f * (float)t / 128.0f;
    float s, c; sincosf(a, &s, &c);
    tw[t] = make_float2(c, -s);
  }
  __syncthreads();
  int f = (t + 64) & 127;
  float ar = 0.f, ai = 0.f;
  for (int z = 0; z < DIMN; ++z){
    float2 v = line[z];
    float2 w = tw[(f*z) & 127];
    ar += v.x*w.x - v.y*w.y;
    ai += v.x*w.y + v.y*w.x;
  }
  float sg = (t & 1) ? -1.f : 1.f;
  volF[(t*DIMN + j)*KXN + k] = make_float2(sg*ar, sg*ai);
}

// ---------------- Image FFT pass 1: mask + rfft over x, sign (-1)^k ----------
// out: AI_T[(b*65+k)*128 + y]
__global__ __launch_bounds__(128) void k_img_fx(const float* __restrict__ imgs,
                                                float2* __restrict__ outT){
  __shared__ float line[DIMN];
  __shared__ float2 tw[DIMN];
  int t = threadIdx.x;
  int bid = blockIdx.x;             // b*128 + y
  int b = bid >> 7, y = bid & 127;
  int dy = y - 64, dx = t - 64;
  float mval = (dy*dy + dx*dx <= 4096) ? 1.f : 0.f;
  line[t] = imgs[bid*DIMN + t] * mval;
  {
    float a = 6.283185307179586f * (float)t / 128.0f;
    float s, c; sincosf(a, &s, &c);
    tw[t] = make_float2(c, -s);
  }
  __syncthreads();
  if (t < KXN){
    float ar = 0.f, ai = 0.f;
    for (int x = 0; x < DIMN; ++x){
      float v = line[x];
      float2 w = tw[(t*x) & 127];
      ar += v*w.x; ai += v*w.y;
    }
    float sg = (t & 1) ? -1.f : 1.f;
    outT[(b*KXN + t)*DIMN + y] = make_float2(sg*ar, sg*ai);
  }
}

// ---------------- Image FFT pass 2: fft over y, shifted output, sign (-1)^j --
// in: AI_T[(b*65+k)*128 + y]   out: fparts[(b*128+j)*65 + k]
__global__ __launch_bounds__(128) void k_img_fy(const float2* __restrict__ inT,
                                                float2* __restrict__ fparts){
  __shared__ float2 line[DIMN];
  __shared__ float2 tw[DIMN];
  int t = threadIdx.x;
  int bid = blockIdx.x;             // b*65 + k
  int b = bid / 65, k = bid - b*65;
  line[t] = inT[(b*KXN + k)*DIMN + t];
  {
    float a = 6.283185307179586f * (float)t / 128.0f;
    float s, c; sincosf(a, &s, &c);
    tw[t] = make_float2(c, -s);
  }
  __syncthreads();
  int f = (t + 64) & 127;
  float ar = 0.f, ai = 0.f;
  for (int y = 0; y < DIMN; ++y){
    float2 v = line[y];
    float2 w = tw[(f*y) & 127];
    ar += v.x*w.x - v.y*w.y;
    ai += v.x*w.y + v.y*w.x;
  }
  float sg = (t & 1) ? -1.f : 1.f;
  fparts[(b*DIMN + t)*KXN + k] = make_float2(sg*ar, sg*ai);
}

// ---------------- Per-(b,opt) rotation columns + expanded euler --------------
// mats[blk*12 + {0..2}]=c1, {3..5}=c2, {6..8}=expanded euler (degrees)
__global__ __launch_bounds__(256) void k_mats(const float* __restrict__ rotm,
                                              float* __restrict__ mats){
  int tid = blockIdx.x*blockDim.x + threadIdx.x;
  if (tid >= NBATCH*NOPT) return;
  int b = tid / NOPT, o = tid - b*NOPT;
  const float* R = rotm + b*9;
  float beta  = acosf(fminf(1.f, fmaxf(-1.f, R[8])));
  float alpha = atan2f(R[5], R[2]);
  float gamma = atan2f(R[7], -R[6]);
  const float DEG = 57.29577951308232f;
  float e0 = alpha*DEG + 3.0f*(float)(o/25      - 2);
  float e1 = beta *DEG + 3.0f*(float)((o/5) % 5 - 2);
  float e2 = gamma*DEG + 3.0f*(float)(o % 5     - 2);
  const float RAD = 0.017453292519943295f;
  float sa, ca, sb, cb, sc, cc;
  sincosf(e0*RAD, &sa, &ca);
  sincosf(e1*RAD, &sb, &cb);
  sincosf(e2*RAD, &sc, &cc);
  float* m = mats + tid*12;
  // c1[i] = R[2-i][1], c2[i] = R[2-i][0] of euler matrix (coords = fy*c1 + fx*c2)
  m[0] = sb*sc;
  m[1] = -sa*cb*sc + ca*cc;
  m[2] = -ca*cb*sc - sa*cc;
  m[3] = -sb*cc;
  m[4] = sa*cb*cc + ca*sc;
  m[5] = ca*cb*cc - sa*sc;
  m[6] = e0; m[7] = e1; m[8] = e2;
}

// ---------------- Main: slice + ctf + conj-mult + partial inverse DFT + argmax
__global__ __launch_bounds__(256) void k_main(const float2* __restrict__ volF,
                                              const float2* __restrict__ fparts,
                                              const float* __restrict__ ctfs,
                                              const float* __restrict__ mats,
                                              float* __restrict__ bestv,
                                              int* __restrict__ besti){
  __shared__ float2 tw[128];        // e^{+2pi i m/128}  (inverse direction)
  __shared__ float2 PT[32*65];      // h-tile of prod
  __shared__ float2 Q[64*65];       // Q[s_local][kx], normalized
  __shared__ float rv[256];
  __shared__ int   ri[256];

  int t = threadIdx.x;
  int blk = blockIdx.x;             // b*125 + o
  int b = blk / NOPT;

  if (t < 128){
    float a = 6.283185307179586f * (float)t / 128.0f;
    float s, c; sincosf(a, &s, &c);
    tw[t] = make_float2(c, s);
  }

  const float* mp = mats + (size_t)blk*12;
  float c1z = mp[0], c1y = mp[1], c1x = mp[2];
  float c2z = mp[3], c2y = mp[4], c2x = mp[5];

  int sl = t & 63;                  // shift index: s = sl - 32
  int g  = t >> 6;                  // wave id -> kx group
  int kx0 = (g == 0) ? 0 : (17 + 16*(g-1));   // 0,17,33,49
  int cnt = (g == 0) ? 17 : 16;
  float qr[17], qi[17];
#pragma unroll
  for (int i = 0; i < 17; ++i){ qr[i] = 0.f; qi[i] = 0.f; }
  int ys = (sl - 32) & 127;

  const float2* fp = fparts + (size_t)b*DIMN*KXN;
  const float*  cf = ctfs   + (size_t)b*DIMN*KXN;

  for (int tile = 0; tile < 4; ++tile){
    int h0 = tile*32;
    // ---- compute prod tile PT[hh][kx] ----
    for (int idx = t; idx < 32*65; idx += 256){
      int hh = idx / 65;
      int kx = idx - hh*65;
      int h = h0 + hh;
      float fy = (float)(h - 64) * 0.0078125f;
      float fx = (float)kx * 0.0078125f;
      float cz = fy*c1z + fx*c2z;
      float cy = fy*c1y + fx*c2y;
      float cx = fy*c1x + fx*c2x;
      bool cj = (cx < 0.f);
      if (cj){ cz = -cz; cy = -cy; cx = -cx; }
      float pz = cz*128.f + 64.f;
      float py = cy*128.f + 64.f;
      float px = cx*128.f;
      float fz0 = floorf(pz), fy0 = floorf(py), fx0 = floorf(px);
      int iz = (int)fz0, iy = (int)fy0, ix = (int)fx0;
      float tz = pz - fz0, ty = py - fy0, tx = px - fx0;
      float ar = 0.f, ai = 0.f;
#pragma unroll
      for (int dz = 0; dz < 2; ++dz){
        int zz = iz + dz;
        if ((unsigned)zz >= 128u) continue;
        float wz = dz ? tz : 1.f - tz;
#pragma unroll
        for (int dyy = 0; dyy < 2; ++dyy){
          int yy = iy + dyy;
          if ((unsigned)yy >= 128u) continue;
          float wzy = wz * (dyy ? ty : 1.f - ty);
#pragma unroll
          for (int dxx = 0; dxx < 2; ++dxx){
            int xx = ix + dxx;
            if ((unsigned)xx >= 65u) continue;
            float w = wzy * (dxx ? tx : 1.f - tx);
            float2 v = volF[((size_t)zz*DIMN + yy)*KXN + xx];
            ar += w*v.x; ai += w*v.y;
          }
        }
      }
      if (cj) ai = -ai;
      float ct = cf[h*KXN + kx];
      float Pr = ar*ct, Pi = ai*ct;
      float2 f = fp[h*KXN + kx];
      // prod = f * conj(P)
      PT[idx] = make_float2(f.x*Pr + f.y*Pi, f.y*Pr - f.x*Pi);
    }
    __syncthreads();
    // ---- accumulate Q over this h-tile ----
    for (int hh = 0; hh < 32; ++hh){
      int h = h0 + hh;
      float2 w = tw[(h*ys) & 127];
      const float2* prow = &PT[hh*65 + kx0];
#pragma unroll
      for (int kk = 0; kk < 17; ++kk){
        if (kk < cnt){
          float2 p = prow[kk];
          qr[kk] += p.x*w.x - p.y*w.y;
          qi[kk] += p.x*w.y + p.y*w.x;
        }
      }
    }
    __syncthreads();
  }

  // ---- write normalized Q: factor (-1)^s / 16384 ----
  {
    float sg = (sl & 1) ? -6.103515625e-05f : 6.103515625e-05f;
#pragma unroll
    for (int kk = 0; kk < 17; ++kk){
      if (kk < cnt) Q[sl*65 + kx0 + kk] = make_float2(qr[kk]*sg, qi[kk]*sg);
    }
  }
  __syncthreads();

  // ---- window DFT over kx + argmax (pocketfft irfft: Im of bins 0,64 dropped)
  float bv = -INFINITY; int bi = 0;
  for (int wi = t; wi < 4096; wi += 256){
    int wy = wi >> 6, wx = wi & 63;
    int xs = (wx - 32) & 127;
    const float2* q = &Q[wy*65];
    float acc = q[0].x + ((wx & 1) ? -q[64].x : q[64].x);
    for (int kx = 1; kx < 64; ++kx){
      float2 w = tw[(kx*xs) & 127];
      float2 v = q[kx];
      acc += 2.f*(v.x*w.x - v.y*w.y);
    }
    if (acc > bv){ bv = acc; bi = wi; }
  }
  rv[t] = bv; ri[t] = bi;
  __syncthreads();
  for (int off = 128; off > 0; off >>= 1){
    if (t < off){
      float v2 = rv[t+off]; int i2 = ri[t+off];
      if (v2 > rv[t] || (v2 == rv[t] && i2 < ri[t])){ rv[t] = v2; ri[t] = i2; }
    }
    __syncthreads();
  }
  if (t == 0){ bestv[blk] = rv[0]; besti[blk] = ri[0]; }
}

// ---------------- Final selection / outputs ----------------------------------
__global__ __launch_bounds__(64) void k_out(const float* __restrict__ bestv,
                                            const int* __restrict__ besti,
                                            const float* __restrict__ mats,
                                            float* __restrict__ out){
  int b = blockIdx.x;
  if (threadIdx.x != 0) return;
  float bv = -INFINITY; int bo = 0;
  for (int o = 0; o < NOPT; ++o){
    float v = bestv[b*NOPT + o];
    if (v > bv){ bv = v; bo = o; }
  }
  float sum = 0.f;
  for (int o = 0; o < NOPT; ++o) sum += bestv[b*NOPT + o];
  float mean = sum * (1.0f/125.0f);
  float ss = 0.f;
  for (int o = 0; o < NOPT; ++o){
    float d = bestv[b*NOPT + o] - mean;
    ss += d*d;
  }
  float stdv = sqrtf(ss * (1.0f/124.0f));

  int wi = besti[b*NOPT + bo];
  int row = (wi >> 6) + 32;
  int col = (wi & 63) + 32;

  // top_v
  out[b] = bv;
  // pred_rotmats from selected expanded euler (degrees)
  const float* mm = mats + (size_t)(b*NOPT + bo)*12;
  const float RAD = 0.017453292519943295f;
  float sa, ca, sb, cb, sc, cc;
  sincosf(mm[6]*RAD, &sa, &ca);
  sincosf(mm[7]*RAD, &sb, &cb);
  sincosf(mm[8]*RAD, &sc, &cc);
  float* R = out + 8 + b*9;
  R[0] = ca*cb*cc - sa*sc;  R[1] = -ca*cb*sc - sa*cc;  R[2] = ca*sb;
  R[3] = sa*cb*cc + ca*sc;  R[4] = -sa*cb*sc + ca*cc;  R[5] = sa*sb;
  R[6] = -sb*cc;            R[7] = sb*sc;              R[8] = cb;
  // pred_shifts_angs = -(shift - 64) * 1.5, order (col,row)
  out[80 + b*2 + 0] = -((float)col - 64.f) * 1.5f;
  out[80 + b*2 + 1] = -((float)row - 64.f) * 1.5f;
  // weight
  float z = (bv - mean) / ((stdv + 1e-6f) * 1.4142135623730951f);
  out[96 + b] = 0.5f*(1.f + erff(z));
}

extern "C" void kernel_launch(void* const* d_in, const int* in_sizes, int n_in,
                              void* d_out, int out_size, void* d_ws, size_t ws_size,
                              hipStream_t stream){
  (void)in_sizes; (void)n_in; (void)out_size; (void)ws_size;
  const float* vol  = (const float*)d_in[0];
  const float* imgs = (const float*)d_in[1];
  const float* ctfs = (const float*)d_in[2];
  const float* rotm = (const float*)d_in[3];
  float* out = (float*)d_out;

  float2* bufA  = (float2*)d_ws;                        // 128*128*65 cplx
  float2* bufB  = bufA + (size_t)DIMN*DIMN*KXN;         // 128*128*65 cplx
  float2* imgT  = bufB + (size_t)DIMN*DIMN*KXN;         // 8*65*128 cplx
  float2* fpart = imgT + (size_t)NBATCH*KXN*DIMN;       // 8*128*65 cplx
  float*  mats  = (float*)(fpart + (size_t)NBATCH*DIMN*KXN); // 1000*12 f32
  float*  bestv = mats + 12000;                         // 1000 f32
  int*    besti = (int*)(bestv + 1000);                 // 1000 i32

  k_vol_fx<<<DIMN*DIMN, 128, 0, stream>>>(vol, bufA);
  k_vol_fy<<<DIMN*KXN, 128, 0, stream>>>(bufA, bufB);
  k_vol_fz<<<DIMN*KXN, 128, 0, stream>>>(bufB, bufA);   // bufA == vol_rfft
  k_img_fx<<<NBATCH*DIMN, 128, 0, stream>>>(imgs, imgT);
  k_img_fy<<<NBATCH*KXN, 128, 0, stream>>>(imgT, fpart);
  k_mats<<<4, 256, 0, stream>>>(rotm, mats);
  k_main<<<NBATCH*NOPT, 256, 0, stream>>>(bufA, fpart, ctfs, mats, bestv, besti);
  k_out<<<NBATCH, 64, 0, stream>>>(bestv, besti, mats, out);
}

// Round 2
// 376.230 us; speedup vs baseline: 1.1211x; 1.1211x over previous
//
#include <hip/hip_runtime.h>
#include <math.h>

#define DIMN 128
#define KXN  65
#define NBATCH 8
#define NOPT 125

// ---------------- Volume FFT pass 1: rfft over x, sign (-1)^k ----------------
// out layout: A_T[(z*65+k)*128 + y]
__global__ __launch_bounds__(128) void k_vol_fx(const float* __restrict__ vol,
                                                float2* __restrict__ outT){
  __shared__ float line[DIMN];
  __shared__ float2 tw[DIMN];
  int t = threadIdx.x;
  int zy = blockIdx.x;              // z*128 + y
  line[t] = vol[zy*DIMN + t];
  {
    float a = 6.283185307179586f * (float)t / 128.0f;
    float s, c; sincosf(a, &s, &c);
    tw[t] = make_float2(c, -s);     // e^{-2pi i t/128}
  }
  __syncthreads();
  if (t < KXN){
    float ar = 0.f, ai = 0.f;
    for (int x = 0; x < DIMN; ++x){
      float v = line[x];
      float2 w = tw[(t*x) & 127];
      ar += v*w.x; ai += v*w.y;
    }
    float sg = (t & 1) ? -1.f : 1.f;
    int z = zy >> 7, y = zy & 127;
    outT[(z*KXN + t)*DIMN + y] = make_float2(sg*ar, sg*ai);
  }
}

// ---------------- Volume FFT pass 2: fft over y, output-shifted j, sign (-1)^j
// in: A_T[(z*65+k)*128 + y]   out: B_T[(j*65+k)*128 + z]
__global__ __launch_bounds__(128) void k_vol_fy(const float2* __restrict__ inT,
                                                float2* __restrict__ outT){
  __shared__ float2 line[DIMN];
  __shared__ float2 tw[DIMN];
  int t = threadIdx.x;
  int bid = blockIdx.x;             // z*65 + k
  int z = bid / 65, k = bid - z*65;
  line[t] = inT[(z*KXN + k)*DIMN + t];
  {
    float a = 6.283185307179586f * (float)t / 128.0f;
    float s, c; sincosf(a, &s, &c);
    tw[t] = make_float2(c, -s);
  }
  __syncthreads();
  int f = (t + 64) & 127;           // DFT frequency for output index t
  float ar = 0.f, ai = 0.f;
  for (int y = 0; y < DIMN; ++y){
    float2 v = line[y];
    float2 w = tw[(f*y) & 127];
    ar += v.x*w.x - v.y*w.y;
    ai += v.x*w.y + v.y*w.x;
  }
  float sg = (t & 1) ? -1.f : 1.f;
  outT[(t*KXN + k)*DIMN + z] = make_float2(sg*ar, sg*ai);
}

// ---------------- Volume FFT pass 3: fft over z, output-shifted i, sign (-1)^i
// in: B_T[(j*65+k)*128 + z]   out: volF[(i*128+j)*65 + k]  (== reference vol_rfft)
__global__ __launch_bounds__(128) void k_vol_fz(const float2* __restrict__ inT,
                                                float2* __restrict__ volF){
  __shared__ float2 line[DIMN];
  __shared__ float2 tw[DIMN];
  int t = threadIdx.x;
  int bid = blockIdx.x;             // j*65 + k
  int j = bid / 65, k = bid - j*65;
  line[t] = inT[(j*KXN + k)*DIMN + t];
  {
    float a = 6.283185307179586f * (float)t / 128.0f;
    float s, c; sincosf(a, &s, &c);
    tw[t] = make_float2(c, -s);
  }
  __syncthreads();
  int f = (t + 64) & 127;
  float ar = 0.f, ai = 0.f;
  for (int z = 0; z < DIMN; ++z){
    float2 v = line[z];
    float2 w = tw[(f*z) & 127];
    ar += v.x*w.x - v.y*w.y;
    ai += v.x*w.y + v.y*w.x;
  }
  float sg = (t & 1) ? -1.f : 1.f;
  volF[(t*DIMN + j)*KXN + k] = make_float2(sg*ar, sg*ai);
}

// ---------------- Image FFT pass 1: mask + rfft over x, sign (-1)^k ----------
// out: AI_T[(b*65+k)*128 + y]
__global__ __launch_bounds__(128) void k_img_fx(const float* __restrict__ imgs,
                                                float2* __restrict__ outT){
  __shared__ float line[DIMN];
  __shared__ float2 tw[DIMN];
  int t = threadIdx.x;
  int bid = blockIdx.x;             // b*128 + y
  int b = bid >> 7, y = bid & 127;
  int dy = y - 64, dx = t - 64;
  float mval = (dy*dy + dx*dx <= 4096) ? 1.f : 0.f;
  line[t] = imgs[bid*DIMN + t] * mval;
  {
    float a = 6.283185307179586f * (float)t / 128.0f;
    float s, c; sincosf(a, &s, &c);
    tw[t] = make_float2(c, -s);
  }
  __syncthreads();
  if (t < KXN){
    float ar = 0.f, ai = 0.f;
    for (int x = 0; x < DIMN; ++x){
      float v = line[x];
      float2 w = tw[(t*x) & 127];
      ar += v*w.x; ai += v*w.y;
    }
    float sg = (t & 1) ? -1.f : 1.f;
    outT[(b*KXN + t)*DIMN + y] = make_float2(sg*ar, sg*ai);
  }
}

// ---------------- Image FFT pass 2: fft over y, shifted output, sign (-1)^j --
// in: AI_T[(b*65+k)*128 + y]   out: fparts[(b*128+j)*65 + k]
__global__ __launch_bounds__(128) void k_img_fy(const float2* __restrict__ inT,
                                                float2* __restrict__ fparts){
  __shared__ float2 line[DIMN];
  __shared__ float2 tw[DIMN];
  int t = threadIdx.x;
  int bid = blockIdx.x;             // b*65 + k
  int b = bid / 65, k = bid - b*65;
  line[t] = inT[(b*KXN + k)*DIMN + t];
  {
    float a = 6.283185307179586f * (float)t / 128.0f;
    float s, c; sincosf(a, &s, &c);
    tw[t] = make_float2(c, -s);
  }
  __syncthreads();
  int f = (t + 64) & 127;
  float ar = 0.f, ai = 0.f;
  for (int y = 0; y < DIMN; ++y){
    float2 v = line[y];
    float2 w = tw[(f*y) & 127];
    ar += v.x*w.x - v.y*w.y;
    ai += v.x*w.y + v.y*w.x;
  }
  float sg = (t & 1) ? -1.f : 1.f;
  fparts[(b*DIMN + t)*KXN + k] = make_float2(sg*ar, sg*ai);
}

// ---------------- Per-(b,opt) rotation columns + expanded euler --------------
__global__ __launch_bounds__(256) void k_mats(const float* __restrict__ rotm,
                                              float* __restrict__ mats){
  int tid = blockIdx.x*blockDim.x + threadIdx.x;
  if (tid >= NBATCH*NOPT) return;
  int b = tid / NOPT, o = tid - b*NOPT;
  const float* R = rotm + b*9;
  float beta  = acosf(fminf(1.f, fmaxf(-1.f, R[8])));
  float alpha = atan2f(R[5], R[2]);
  float gamma = atan2f(R[7], -R[6]);
  const float DEG = 57.29577951308232f;
  float e0 = alpha*DEG + 3.0f*(float)(o/25      - 2);
  float e1 = beta *DEG + 3.0f*(float)((o/5) % 5 - 2);
  float e2 = gamma*DEG + 3.0f*(float)(o % 5     - 2);
  const float RAD = 0.017453292519943295f;
  float sa, ca, sb, cb, sc, cc;
  sincosf(e0*RAD, &sa, &ca);
  sincosf(e1*RAD, &sb, &cb);
  sincosf(e2*RAD, &sc, &cc);
  float* m = mats + tid*12;
  m[0] = sb*sc;
  m[1] = -sa*cb*sc + ca*cc;
  m[2] = -ca*cb*sc - sa*cc;
  m[3] = -sb*cc;
  m[4] = sa*cb*cc + ca*sc;
  m[5] = ca*cb*cc - sa*sc;
  m[6] = e0; m[7] = e1; m[8] = e2;
}

// ---- prod element: trilinear slice sample * ctf, then f * conj(P) -----------
__device__ __forceinline__ float2 prod_elem(int h, int kx,
                                            float c1z, float c1y, float c1x,
                                            float c2z, float c2y, float c2x,
                                            const float2* __restrict__ volF,
                                            const float2* __restrict__ fp,
                                            const float*  __restrict__ cf){
  float fyv = (float)(h - 64) * 0.0078125f;
  float fxv = (float)kx * 0.0078125f;
  float cz = fyv*c1z + fxv*c2z;
  float cy = fyv*c1y + fxv*c2y;
  float cx = fyv*c1x + fxv*c2x;
  bool cj = (cx < 0.f);
  if (cj){ cz = -cz; cy = -cy; cx = -cx; }
  float pz = cz*128.f + 64.f;
  float py = cy*128.f + 64.f;
  float px = cx*128.f;
  float fz = floorf(pz), fy = floorf(py), fx = floorf(px);
  int iz = (int)fz, iy = (int)fy, ix = (int)fx;
  float tz = pz - fz, ty = py - fy, tx = px - fx;
  float wz0 = ((unsigned)iz      < 128u) ? 1.f - tz : 0.f;
  float wz1 = ((unsigned)(iz+1)  < 128u) ? tz       : 0.f;
  float wy0 = ((unsigned)iy      < 128u) ? 1.f - ty : 0.f;
  float wy1 = ((unsigned)(iy+1)  < 128u) ? ty       : 0.f;
  float wx0 = ((unsigned)ix      < 65u)  ? 1.f - tx : 0.f;
  float wx1 = ((unsigned)(ix+1)  < 65u)  ? tx       : 0.f;
  int iz0 = min(max(iz,   0), 127), iz1 = min(max(iz+1, 0), 127);
  int iy0 = min(max(iy,   0), 127), iy1 = min(max(iy+1, 0), 127);
  int ix0 = min(max(ix,   0), 64),  ix1 = min(max(ix+1, 0), 64);
  const float2* r00 = volF + (size_t)(iz0*128 + iy0)*65;
  const float2* r01 = volF + (size_t)(iz0*128 + iy1)*65;
  const float2* r10 = volF + (size_t)(iz1*128 + iy0)*65;
  const float2* r11 = volF + (size_t)(iz1*128 + iy1)*65;
  float2 v000 = r00[ix0], v001 = r00[ix1];
  float2 v010 = r01[ix0], v011 = r01[ix1];
  float2 v100 = r10[ix0], v101 = r10[ix1];
  float2 v110 = r11[ix0], v111 = r11[ix1];
  float w00 = wz0*wy0, w01 = wz0*wy1, w10 = wz1*wy0, w11 = wz1*wy1;
  float ar = w00*(wx0*v000.x + wx1*v001.x) + w01*(wx0*v010.x + wx1*v011.x)
           + w10*(wx0*v100.x + wx1*v101.x) + w11*(wx0*v110.x + wx1*v111.x);
  float ai = w00*(wx0*v000.y + wx1*v001.y) + w01*(wx0*v010.y + wx1*v011.y)
           + w10*(wx0*v100.y + wx1*v101.y) + w11*(wx0*v110.y + wx1*v111.y);
  if (cj) ai = -ai;
  float ct = cf[h*KXN + kx];
  float Pr = ar*ct, Pi = ai*ct;
  float2 f = fp[h*KXN + kx];
  return make_float2(f.x*Pr + f.y*Pi, f.y*Pr - f.x*Pi);   // f * conj(P)
}

// ---------------- Main: slice + ctf + conj-mult + partial inverse DFT + argmax
// LDS: BUF is PT[64][66] during tiles, then Q[65][64] (transposed) for phase C.
__global__ __launch_bounds__(256, 4) void k_main(const float2* __restrict__ volF,
                                                 const float2* __restrict__ fparts,
                                                 const float* __restrict__ ctfs,
                                                 const float* __restrict__ mats,
                                                 float* __restrict__ bestv,
                                                 int* __restrict__ besti){
  __shared__ __align__(16) float2 BUF[4224];   // max(64*66, 65*64) = 4224
  __shared__ float2 twsh[128];                 // e^{+2pi i m/128}
  __shared__ float rvw[4];
  __shared__ int   riw[4];

  int t = threadIdx.x;
  int blk = blockIdx.x;             // b*125 + o
  int b = blk / NOPT;

  if (t < 128){
    float a = 6.283185307179586f * (float)t / 128.0f;
    float s, c; sincosf(a, &s, &c);
    twsh[t] = make_float2(c, s);
  }

  const float* mp = mats + (size_t)blk*12;
  float c1z = mp[0], c1y = mp[1], c1x = mp[2];
  float c2z = mp[3], c2y = mp[4], c2x = mp[5];

  int sl = t & 63;                  // shift row: s = sl - 32
  int g  = t >> 6;                  // wave id -> kx group
  int kx0 = g * 16;                 // wave3 additionally owns kx=64
  float qr[17], qi[17];
#pragma unroll
  for (int i = 0; i < 17; ++i){ qr[i] = 0.f; qi[i] = 0.f; }
  int ys = (sl - 32) & 127;

  const float2* fp = fparts + (size_t)b*DIMN*KXN;
  const float*  cf = ctfs   + (size_t)b*DIMN*KXN;

  for (int t2 = 0; t2 < 2; ++t2){
    int h0 = t2 << 6;
    // ---- compute prod tile PT[hh][kx], row stride 66 (16B-aligned rows) ----
    {
      int hh = t / 65, kx = t - hh*65;           // t<256 -> hh in 0..3
#pragma unroll 1
      for (int r = 0; r < 16; ++r){
        BUF[hh*66 + kx] = prod_elem(h0 + hh, kx, c1z,c1y,c1x, c2z,c2y,c2x, volF, fp, cf);
        kx += 61; hh += 3;
        if (kx >= 65){ kx -= 65; ++hh; }
      }
      if (t < 64){  // tail: idx = t + 4096 -> hh = 63, kx = t+1? no: compute directly
        int idx = t + 4096;
        int hh2 = idx / 65, kx2 = idx - hh2*65;
        BUF[hh2*66 + kx2] = prod_elem(h0 + hh2, kx2, c1z,c1y,c1x, c2z,c2y,c2x, volF, fp, cf);
      }
    }
    __syncthreads();
    // ---- accumulate Q over this h-tile via rotation recurrence ----
    float2 stp = twsh[ys];          // e^{+2pi i ys/128}
    float wr = 1.f, wi = 0.f;       // w = e^{+2pi i (h0*ys)/128}
    if (t2 == 1 && (ys & 1)) wr = -1.f;
#pragma unroll 1
    for (int hh = 0; hh < 64; ++hh){
      const float4* p4 = (const float4*)(BUF + hh*66 + kx0);
#pragma unroll
      for (int kk = 0; kk < 8; ++kk){
        float4 p = p4[kk];
        qr[2*kk]   += p.x*wr - p.y*wi;
        qi[2*kk]   += p.x*wi + p.y*wr;
        qr[2*kk+1] += p.z*wr - p.w*wi;
        qi[2*kk+1] += p.z*wi + p.w*wr;
      }
      if (g == 3){
        float2 p = BUF[hh*66 + 64];
        qr[16] += p.x*wr - p.y*wi;
        qi[16] += p.x*wi + p.y*wr;
      }
      float nr = wr*stp.x - wi*stp.y;
      wi = wr*stp.y + wi*stp.x;
      wr = nr;
    }
    __syncthreads();
  }

  // ---- write normalized Q transposed: Q[kx][sl], factor (-1)^s / 16384 ----
  {
    float sg = (sl & 1) ? -6.103515625e-05f : 6.103515625e-05f;
#pragma unroll
    for (int kk = 0; kk < 16; ++kk){
      BUF[(kx0 + kk)*64 + sl] = make_float2(qr[kk]*sg, qi[kk]*sg);
    }
    if (g == 3) BUF[64*64 + sl] = make_float2(qr[16]*sg, qi[16]*sg);
  }
  __syncthreads();

  // ---- window DFT over kx + argmax (pocketfft irfft: Im of bins 0,64 dropped)
  float bv = -INFINITY; int bi = 0;
#pragma unroll 1
  for (int wi2 = t; wi2 < 4096; wi2 += 256){
    int wy = wi2 >> 6, wx = wi2 & 63;
    int xs = (wx - 32) & 127;
    float2 st = twsh[xs];
    const float2* q = BUF + wy;
    float q0  = q[0].x;
    float q64 = q[64*64].x;
    float acc = q0 + ((wx & 1) ? -q64 : q64);
    float wr = st.x, wiq = st.y;
    const float2* qp = q + 64;
#pragma unroll 1
    for (int k = 1; k < 64; ++k){
      float2 v = *qp; qp += 64;
      acc += 2.f*(v.x*wr - v.y*wiq);
      float nr = wr*st.x - wiq*st.y;
      wiq = wr*st.y + wiq*st.x;
      wr = nr;
    }
    if (acc > bv){ bv = acc; bi = wi2; }
  }
  // wave-level shuffle reduce (lowest index wins ties)
#pragma unroll
  for (int off = 32; off > 0; off >>= 1){
    float v2 = __shfl_down(bv, off, 64);
    int   i2 = __shfl_down(bi, off, 64);
    if (v2 > bv || (v2 == bv && i2 < bi)){ bv = v2; bi = i2; }
  }
  if ((t & 63) == 0){ rvw[g] = bv; riw[g] = bi; }
  __syncthreads();
  if (t == 0){
    float fv = rvw[0]; int fi = riw[0];
#pragma unroll
    for (int wv = 1; wv < 4; ++wv){
      float v2 = rvw[wv]; int i2 = riw[wv];
      if (v2 > fv || (v2 == fv && i2 < fi)){ fv = v2; fi = i2; }
    }
    bestv[blk] = fv; besti[blk] = fi;
  }
}

// ---------------- Final selection / outputs ----------------------------------
__global__ __launch_bounds__(64) void k_out(const float* __restrict__ bestv,
                                            const int* __restrict__ besti,
                                            const float* __restrict__ mats,
                                            float* __restrict__ out){
  int b = blockIdx.x;
  if (threadIdx.x != 0) return;
  float bv = -INFINITY; int bo = 0;
  for (int o = 0; o < NOPT; ++o){
    float v = bestv[b*NOPT + o];
    if (v > bv){ bv = v; bo = o; }
  }
  float sum = 0.f;
  for (int o = 0; o < NOPT; ++o) sum += bestv[b*NOPT + o];
  float mean = sum * (1.0f/125.0f);
  float ss = 0.f;
  for (int o = 0; o < NOPT; ++o){
    float d = bestv[b*NOPT + o] - mean;
    ss += d*d;
  }
  float stdv = sqrtf(ss * (1.0f/124.0f));

  int wi = besti[b*NOPT + bo];
  int row = (wi >> 6) + 32;
  int col = (wi & 63) + 32;

  out[b] = bv;
  const float* mm = mats + (size_t)(b*NOPT + bo)*12;
  const float RAD = 0.017453292519943295f;
  float sa, ca, sb, cb, sc, cc;
  sincosf(mm[6]*RAD, &sa, &ca);
  sincosf(mm[7]*RAD, &sb, &cb);
  sincosf(mm[8]*RAD, &sc, &cc);
  float* R = out + 8 + b*9;
  R[0] = ca*cb*cc - sa*sc;  R[1] = -ca*cb*sc - sa*cc;  R[2] = ca*sb;
  R[3] = sa*cb*cc + ca*sc;  R[4] = -sa*cb*sc + ca*cc;  R[5] = sa*sb;
  R[6] = -sb*cc;            R[7] = sb*sc;              R[8] = cb;
  out[80 + b*2 + 0] = -((float)col - 64.f) * 1.5f;
  out[80 + b*2 + 1] = -((float)row - 64.f) * 1.5f;
  float z = (bv - mean) / ((stdv + 1e-6f) * 1.4142135623730951f);
  out[96 + b] = 0.5f*(1.f + erff(z));
}

extern "C" void kernel_launch(void* const* d_in, const int* in_sizes, int n_in,
                              void* d_out, int out_size, void* d_ws, size_t ws_size,
                              hipStream_t stream){
  (void)in_sizes; (void)n_in; (void)out_size; (void)ws_size;
  const float* vol  = (const float*)d_in[0];
  const float* imgs = (const float*)d_in[1];
  const float* ctfs = (const float*)d_in[2];
  const float* rotm = (const float*)d_in[3];
  float* out = (float*)d_out;

  float2* bufA  = (float2*)d_ws;                        // 128*128*65 cplx
  float2* bufB  = bufA + (size_t)DIMN*DIMN*KXN;         // 128*128*65 cplx
  float2* imgT  = bufB + (size_t)DIMN*DIMN*KXN;         // 8*65*128 cplx
  float2* fpart = imgT + (size_t)NBATCH*KXN*DIMN;       // 8*128*65 cplx
  float*  mats  = (float*)(fpart + (size_t)NBATCH*DIMN*KXN); // 1000*12 f32
  float*  bestv = mats + 12000;                         // 1000 f32
  int*    besti = (int*)(bestv + 1000);                 // 1000 i32

  k_vol_fx<<<DIMN*DIMN, 128, 0, stream>>>(vol, bufA);
  k_vol_fy<<<DIMN*KXN, 128, 0, stream>>>(bufA, bufB);
  k_vol_fz<<<DIMN*KXN, 128, 0, stream>>>(bufB, bufA);   // bufA == vol_rfft
  k_img_fx<<<NBATCH*DIMN, 128, 0, stream>>>(imgs, imgT);
  k_img_fy<<<NBATCH*KXN, 128, 0, stream>>>(imgT, fpart);
  k_mats<<<4, 256, 0, stream>>>(rotm, mats);
  k_main<<<NBATCH*NOPT, 256, 0, stream>>>(bufA, fpart, ctfs, mats, bestv, besti);
  k_out<<<NBATCH, 64, 0, stream>>>(bestv, besti, mats, out);
}

// Round 3
// 317.265 us; speedup vs baseline: 1.3294x; 1.1859x over previous
//
#include <hip/hip_runtime.h>
#include <math.h>

#define DIMN 128
#define KXN  65
#define NBATCH 8
#define NOPT 125

// ============ wave-level 128-point FFT (radix-2 DIF, 2 points/lane) ==========
// Input: A = x[lane], B = x[lane+64] (natural order).
// Output: A = X[e], B = X[e+1], where e = bitrev7(lane) (even).
// X[k] = sum_n x[n] * exp(sigma*2*pi*i*n*k/128); twiddles precomputed per lane.
__device__ __forceinline__ void fft_twiddles(float sigma, int lane,
                                             float* twr, float* twi){
  const float W = 0.04908738521234052f;   // 2*pi/128
  float s, c;
  sincosf(sigma * W * (float)lane, &s, &c);
  twr[0] = c; twi[0] = s;
#pragma unroll
  for (int st = 1; st <= 6; ++st){
    int off = 64 >> st;
    int m = (lane & (off - 1)) << st;
    sincosf(sigma * W * (float)m, &s, &c);
    bool hi = (lane & off) != 0;
    twr[st] = hi ? c : 1.f;
    twi[st] = hi ? s : 0.f;
  }
}

__device__ __forceinline__ void wave_fft128(float& Ar, float& Ai, float& Br, float& Bi,
                                            const float* twr, const float* twi, int lane){
  // stage 0: in-lane butterfly between positions lane and lane+64
  {
    float dr = Ar - Br, di = Ai - Bi;
    Ar += Br; Ai += Bi;
    float nr = dr*twr[0] - di*twi[0];
    Bi = dr*twi[0] + di*twr[0];
    Br = nr;
  }
#pragma unroll
  for (int s = 1; s <= 6; ++s){
    int off = 64 >> s;
    float sgn = (lane & off) ? -1.f : 1.f;
    float pr = __shfl_xor(Ar, off, 64);
    float pi = __shfl_xor(Ai, off, 64);
    float dr = fmaf(Ar, sgn, pr);
    float di = fmaf(Ai, sgn, pi);
    Ar = dr*twr[s] - di*twi[s];
    Ai = dr*twi[s] + di*twr[s];
    pr = __shfl_xor(Br, off, 64);
    pi = __shfl_xor(Bi, off, 64);
    dr = fmaf(Br, sgn, pr);
    di = fmaf(Bi, sgn, pi);
    Br = dr*twr[s] - di*twi[s];
    Bi = dr*twi[s] + di*twr[s];
  }
}

// ---------------- Volume FFT pass 1: rfft over x, sign (-1)^k ----------------
// out layout: A_T[(z*65+k)*128 + y]
__global__ __launch_bounds__(128) void k_vol_fx(const float* __restrict__ vol,
                                                float2* __restrict__ outT){
  __shared__ float line[DIMN];
  int t = threadIdx.x;
  int zy = blockIdx.x;              // z*128 + y
  line[t] = vol[zy*DIMN + t];
  __syncthreads();
  if (t < KXN){
    float ss, cc; sincosf(-0.04908738521234052f*(float)t, &ss, &cc);
    float wr = 1.f, wi = 0.f;       // w = e^{-2pi i t x/128}
    float ar = 0.f, ai = 0.f;
    for (int x = 0; x < DIMN; ++x){
      float v = line[x];
      ar = fmaf(v, wr, ar); ai = fmaf(v, wi, ai);
      float nr = wr*cc - wi*ss; wi = wr*ss + wi*cc; wr = nr;
    }
    float sg = (t & 1) ? -1.f : 1.f;
    int z = zy >> 7, y = zy & 127;
    outT[(z*KXN + t)*DIMN + y] = make_float2(sg*ar, sg*ai);
  }
}

// ---------------- Volume FFT pass 2: fft over y, output-shifted j, sign (-1)^j
__global__ __launch_bounds__(128) void k_vol_fy(const float2* __restrict__ inT,
                                                float2* __restrict__ outT){
  __shared__ float2 line[DIMN];
  int t = threadIdx.x;
  int bid = blockIdx.x;             // z*65 + k
  int z = bid / 65, k = bid - z*65;
  line[t] = inT[(z*KXN + k)*DIMN + t];
  __syncthreads();
  int f = (t + 64) & 127;
  float ss, cc; sincosf(-0.04908738521234052f*(float)f, &ss, &cc);
  float wr = 1.f, wi = 0.f;
  float ar = 0.f, ai = 0.f;
  for (int y = 0; y < DIMN; ++y){
    float2 v = line[y];
    ar += v.x*wr - v.y*wi;
    ai += v.x*wi + v.y*wr;
    float nr = wr*cc - wi*ss; wi = wr*ss + wi*cc; wr = nr;
  }
  float sg = (t & 1) ? -1.f : 1.f;
  outT[(t*KXN + k)*DIMN + z] = make_float2(sg*ar, sg*ai);
}

// ---------------- Volume FFT pass 3: fft over z, output-shifted i, sign (-1)^i
__global__ __launch_bounds__(128) void k_vol_fz(const float2* __restrict__ inT,
                                                float2* __restrict__ volF){
  __shared__ float2 line[DIMN];
  int t = threadIdx.x;
  int bid = blockIdx.x;             // j*65 + k
  int j = bid / 65, k = bid - j*65;
  line[t] = inT[(j*KXN + k)*DIMN + t];
  __syncthreads();
  int f = (t + 64) & 127;
  float ss, cc; sincosf(-0.04908738521234052f*(float)f, &ss, &cc);
  float wr = 1.f, wi = 0.f;
  float ar = 0.f, ai = 0.f;
  for (int z = 0; z < DIMN; ++z){
    float2 v = line[z];
    ar += v.x*wr - v.y*wi;
    ai += v.x*wi + v.y*wr;
    float nr = wr*cc - wi*ss; wi = wr*ss + wi*cc; wr = nr;
  }
  float sg = (t & 1) ? -1.f : 1.f;
  volF[(t*DIMN + j)*KXN + k] = make_float2(sg*ar, sg*ai);
}

// ---------------- Image FFT pass 1: mask + rfft over x, sign (-1)^k ----------
__global__ __launch_bounds__(128) void k_img_fx(const float* __restrict__ imgs,
                                                float2* __restrict__ outT){
  __shared__ float line[DIMN];
  int t = threadIdx.x;
  int bid = blockIdx.x;             // b*128 + y
  int b = bid >> 7, y = bid & 127;
  int dy = y - 64, dx = t - 64;
  float mval = (dy*dy + dx*dx <= 4096) ? 1.f : 0.f;
  line[t] = imgs[bid*DIMN + t] * mval;
  __syncthreads();
  if (t < KXN){
    float ss, cc; sincosf(-0.04908738521234052f*(float)t, &ss, &cc);
    float wr = 1.f, wi = 0.f;
    float ar = 0.f, ai = 0.f;
    for (int x = 0; x < DIMN; ++x){
      float v = line[x];
      ar = fmaf(v, wr, ar); ai = fmaf(v, wi, ai);
      float nr = wr*cc - wi*ss; wi = wr*ss + wi*cc; wr = nr;
    }
    float sg = (t & 1) ? -1.f : 1.f;
    outT[(b*KXN + t)*DIMN + y] = make_float2(sg*ar, sg*ai);
  }
}

// ---------------- Image FFT pass 2: fft over y, shifted output, sign (-1)^j --
__global__ __launch_bounds__(128) void k_img_fy(const float2* __restrict__ inT,
                                                float2* __restrict__ fparts){
  __shared__ float2 line[DIMN];
  int t = threadIdx.x;
  int bid = blockIdx.x;             // b*65 + k
  int b = bid / 65, k = bid - b*65;
  line[t] = inT[(b*KXN + k)*DIMN + t];
  __syncthreads();
  int f = (t + 64) & 127;
  float ss, cc; sincosf(-0.04908738521234052f*(float)f, &ss, &cc);
  float wr = 1.f, wi = 0.f;
  float ar = 0.f, ai = 0.f;
  for (int y = 0; y < DIMN; ++y){
    float2 v = line[y];
    ar += v.x*wr - v.y*wi;
    ai += v.x*wi + v.y*wr;
    float nr = wr*cc - wi*ss; wi = wr*ss + wi*cc; wr = nr;
  }
  float sg = (t & 1) ? -1.f : 1.f;
  fparts[(b*DIMN + t)*KXN + k] = make_float2(sg*ar, sg*ai);
}

// ---------------- Per-(b,opt) rotation columns + expanded euler --------------
__global__ __launch_bounds__(256) void k_mats(const float* __restrict__ rotm,
                                              float* __restrict__ mats){
  int tid = blockIdx.x*blockDim.x + threadIdx.x;
  if (tid >= NBATCH*NOPT) return;
  int b = tid / NOPT, o = tid - b*NOPT;
  const float* R = rotm + b*9;
  float beta  = acosf(fminf(1.f, fmaxf(-1.f, R[8])));
  float alpha = atan2f(R[5], R[2]);
  float gamma = atan2f(R[7], -R[6]);
  const float DEG = 57.29577951308232f;
  float e0 = alpha*DEG + 3.0f*(float)(o/25      - 2);
  float e1 = beta *DEG + 3.0f*(float)((o/5) % 5 - 2);
  float e2 = gamma*DEG + 3.0f*(float)(o % 5     - 2);
  const float RAD = 0.017453292519943295f;
  float sa, ca, sb, cb, sc, cc;
  sincosf(e0*RAD, &sa, &ca);
  sincosf(e1*RAD, &sb, &cb);
  sincosf(e2*RAD, &sc, &cc);
  float* m = mats + tid*12;
  m[0] = sb*sc;
  m[1] = -sa*cb*sc + ca*cc;
  m[2] = -ca*cb*sc - sa*cc;
  m[3] = -sb*cc;
  m[4] = sa*cb*cc + ca*sc;
  m[5] = ca*cb*cc - sa*sc;
  m[6] = e0; m[7] = e1; m[8] = e2;
}

// ---- prod element: trilinear slice sample * ctf, then f * conj(P) -----------
__device__ __forceinline__ float2 prod_elem(int h, int kx,
                                            float c1z, float c1y, float c1x,
                                            float c2z, float c2y, float c2x,
                                            const float2* __restrict__ volF,
                                            const float2* __restrict__ fp,
                                            const float*  __restrict__ cf){
  float fyv = (float)(h - 64) * 0.0078125f;
  float fxv = (float)kx * 0.0078125f;
  float cz = fyv*c1z + fxv*c2z;
  float cy = fyv*c1y + fxv*c2y;
  float cx = fyv*c1x + fxv*c2x;
  bool cj = (cx < 0.f);
  if (cj){ cz = -cz; cy = -cy; cx = -cx; }
  float pz = cz*128.f + 64.f;
  float py = cy*128.f + 64.f;
  float px = cx*128.f;
  float fz = floorf(pz), fy = floorf(py), fx = floorf(px);
  int iz = (int)fz, iy = (int)fy, ix = (int)fx;
  float tz = pz - fz, ty = py - fy, tx = px - fx;
  float wz0 = ((unsigned)iz      < 128u) ? 1.f - tz : 0.f;
  float wz1 = ((unsigned)(iz+1)  < 128u) ? tz       : 0.f;
  float wy0 = ((unsigned)iy      < 128u) ? 1.f - ty : 0.f;
  float wy1 = ((unsigned)(iy+1)  < 128u) ? ty       : 0.f;
  float wx0 = ((unsigned)ix      < 65u)  ? 1.f - tx : 0.f;
  float wx1 = ((unsigned)(ix+1)  < 65u)  ? tx       : 0.f;
  int iz0 = min(max(iz,   0), 127), iz1 = min(max(iz+1, 0), 127);
  int iy0 = min(max(iy,   0), 127), iy1 = min(max(iy+1, 0), 127);
  int ix0 = min(max(ix,   0), 64),  ix1 = min(max(ix+1, 0), 64);
  const float2* r00 = volF + (size_t)(iz0*128 + iy0)*65;
  const float2* r01 = volF + (size_t)(iz0*128 + iy1)*65;
  const float2* r10 = volF + (size_t)(iz1*128 + iy0)*65;
  const float2* r11 = volF + (size_t)(iz1*128 + iy1)*65;
  float2 v000 = r00[ix0], v001 = r00[ix1];
  float2 v010 = r01[ix0], v011 = r01[ix1];
  float2 v100 = r10[ix0], v101 = r10[ix1];
  float2 v110 = r11[ix0], v111 = r11[ix1];
  float w00 = wz0*wy0, w01 = wz0*wy1, w10 = wz1*wy0, w11 = wz1*wy1;
  float ar = w00*(wx0*v000.x + wx1*v001.x) + w01*(wx0*v010.x + wx1*v011.x)
           + w10*(wx0*v100.x + wx1*v101.x) + w11*(wx0*v110.x + wx1*v111.x);
  float ai = w00*(wx0*v000.y + wx1*v001.y) + w01*(wx0*v010.y + wx1*v011.y)
           + w10*(wx0*v100.y + wx1*v101.y) + w11*(wx0*v110.y + wx1*v111.y);
  if (cj) ai = -ai;
  float ct = cf[h*KXN + kx];
  float Pr = ar*ct, Pi = ai*ct;
  float2 f = fp[h*KXN + kx];
  return make_float2(f.x*Pr + f.y*Pi, f.y*Pr - f.x*Pi);   // f * conj(P)
}

// ---------------- Main: slice + ctf + conj-mult + wave-FFT + argmax ----------
// Phase B: per kx column, FFT over h (sign +) -> window rows of Q[s][kx].
// Phase C: per row-pair, Hermitian-pack 2 real-output irfft rows into 1 FFT.
__global__ __launch_bounds__(256, 4) void k_main(const float2* __restrict__ volF,
                                                 const float2* __restrict__ fparts,
                                                 const float* __restrict__ ctfs,
                                                 const float* __restrict__ mats,
                                                 float* __restrict__ bestv,
                                                 int* __restrict__ besti){
  __shared__ float2 Q[64*65];       // Q[s][kx], normalized, window rows only
  __shared__ float rvw[4];
  __shared__ int   riw[4];

  int t = threadIdx.x, lane = t & 63, g = t >> 6;
  int blk = blockIdx.x;             // b*125 + o
  int b = blk / NOPT;

  float twr[7], twi[7];
  fft_twiddles(1.f, lane, twr, twi);   // sign + (inverse direction), shared B&C

  const float* mp = mats + (size_t)blk*12;
  float c1z = mp[0], c1y = mp[1], c1x = mp[2];
  float c2z = mp[3], c2y = mp[4], c2x = mp[5];
  const float2* fp = fparts + (size_t)b*DIMN*KXN;
  const float*  cf = ctfs   + (size_t)b*DIMN*KXN;

  int e = (int)(__brev((unsigned)lane) >> 25);   // bitrev7(lane), even
  int slA = (e + 32) & 127;                      // window row for bin e
  bool inwin = (slA < 64);
  const float NRM = 6.103515625e-05f;            // 1/16384

  // ---- Phase A+B: prod columns -> FFT over h -> Q rows ----
#pragma unroll 1
  for (int ci = 0; ci < 17; ++ci){
    int kx = 4*ci + g;
    if (kx > 64) break;                          // wave-uniform
    float2 A = prod_elem(lane,      kx, c1z,c1y,c1x, c2z,c2y,c2x, volF, fp, cf);
    float2 B = prod_elem(lane + 64, kx, c1z,c1y,c1x, c2z,c2y,c2x, volF, fp, cf);
    wave_fft128(A.x, A.y, B.x, B.y, twr, twi, lane);
    if (inwin){
      Q[slA*KXN + kx]     = make_float2( A.x*NRM,  A.y*NRM);   // row slA   (even, +)
      Q[(slA+1)*KXN + kx] = make_float2(-B.x*NRM, -B.y*NRM);   // row slA+1 (odd,  -)
    }
  }
  __syncthreads();

  // ---- Phase C: 32 row-pair FFTs over kx (Hermitian-packed), fused argmax ----
  float bv = -INFINITY; int bi = 0;
  int ra = 64 - lane;                            // B-side source column (lane0 -> 64)
#pragma unroll 1
  for (int pi = 0; pi < 8; ++pi){
    int r1 = (8*g + pi) << 1;                    // rows r1, r1+1
    float2 a1 = Q[r1*KXN + lane];
    float2 a2 = Q[(r1+1)*KXN + lane];
    float2 b1 = Q[r1*KXN + ra];
    float2 b2 = Q[(r1+1)*KXN + ra];
    if (lane == 0){ a1.y = 0.f; a2.y = 0.f; b1.y = 0.f; b2.y = 0.f; }
    else { b1.y = -b1.y; b2.y = -b2.y; }         // conj for mirrored bins
    float zAr = a1.x - a2.y, zAi = a1.y + a2.x;  // z = x1 + i*x2
    float zBr = b1.x - b2.y, zBi = b1.y + b2.x;
    wave_fft128(zAr, zAi, zBr, zBi, twr, twi, lane);
    if (inwin){
      int i0 = (r1 << 6) + slA;                  // row r1, wx = slA
      // bin e:   Re -> row r1, Im -> row r1+1
      if (zAr > bv || (zAr == bv && i0      < bi)){ bv = zAr; bi = i0; }
      if (zAi > bv || (zAi == bv && i0+64   < bi)){ bv = zAi; bi = i0+64; }
      // bin e+1: wx = slA+1
      if (zBr > bv || (zBr == bv && i0+1    < bi)){ bv = zBr; bi = i0+1; }
      if (zBi > bv || (zBi == bv && i0+65   < bi)){ bv = zBi; bi = i0+65; }
    }
  }

  // wave-level shuffle reduce (lowest index wins ties)
#pragma unroll
  for (int off = 32; off > 0; off >>= 1){
    float v2 = __shfl_down(bv, off, 64);
    int   i2 = __shfl_down(bi, off, 64);
    if (v2 > bv || (v2 == bv && i2 < bi)){ bv = v2; bi = i2; }
  }
  if (lane == 0){ rvw[g] = bv; riw[g] = bi; }
  __syncthreads();
  if (t == 0){
    float fv = rvw[0]; int fi = riw[0];
#pragma unroll
    for (int wv = 1; wv < 4; ++wv){
      float v2 = rvw[wv]; int i2 = riw[wv];
      if (v2 > fv || (v2 == fv && i2 < fi)){ fv = v2; fi = i2; }
    }
    bestv[blk] = fv; besti[blk] = fi;
  }
}

// ---------------- Final selection / outputs ----------------------------------
__global__ __launch_bounds__(64) void k_out(const float* __restrict__ bestv,
                                            const int* __restrict__ besti,
                                            const float* __restrict__ mats,
                                            float* __restrict__ out){
  int b = blockIdx.x;
  if (threadIdx.x != 0) return;
  float bv = -INFINITY; int bo = 0;
  for (int o = 0; o < NOPT; ++o){
    float v = bestv[b*NOPT + o];
    if (v > bv){ bv = v; bo = o; }
  }
  float sum = 0.f;
  for (int o = 0; o < NOPT; ++o) sum += bestv[b*NOPT + o];
  float mean = sum * (1.0f/125.0f);
  float ss = 0.f;
  for (int o = 0; o < NOPT; ++o){
    float d = bestv[b*NOPT + o] - mean;
    ss += d*d;
  }
  float stdv = sqrtf(ss * (1.0f/124.0f));

  int wi = besti[b*NOPT + bo];
  int row = (wi >> 6) + 32;
  int col = (wi & 63) + 32;

  out[b] = bv;
  const float* mm = mats + (size_t)(b*NOPT + bo)*12;
  const float RAD = 0.017453292519943295f;
  float sa, ca, sb, cb, sc, cc;
  sincosf(mm[6]*RAD, &sa, &ca);
  sincosf(mm[7]*RAD, &sb, &cb);
  sincosf(mm[8]*RAD, &sc, &cc);
  float* R = out + 8 + b*9;
  R[0] = ca*cb*cc - sa*sc;  R[1] = -ca*cb*sc - sa*cc;  R[2] = ca*sb;
  R[3] = sa*cb*cc + ca*sc;  R[4] = -sa*cb*sc + ca*cc;  R[5] = sa*sb;
  R[6] = -sb*cc;            R[7] = sb*sc;              R[8] = cb;
  out[80 + b*2 + 0] = -((float)col - 64.f) * 1.5f;
  out[80 + b*2 + 1] = -((float)row - 64.f) * 1.5f;
  float z = (bv - mean) / ((stdv + 1e-6f) * 1.4142135623730951f);
  out[96 + b] = 0.5f*(1.f + erff(z));
}

extern "C" void kernel_launch(void* const* d_in, const int* in_sizes, int n_in,
                              void* d_out, int out_size, void* d_ws, size_t ws_size,
                              hipStream_t stream){
  (void)in_sizes; (void)n_in; (void)out_size; (void)ws_size;
  const float* vol  = (const float*)d_in[0];
  const float* imgs = (const float*)d_in[1];
  const float* ctfs = (const float*)d_in[2];
  const float* rotm = (const float*)d_in[3];
  float* out = (float*)d_out;

  float2* bufA  = (float2*)d_ws;                        // 128*128*65 cplx
  float2* bufB  = bufA + (size_t)DIMN*DIMN*KXN;         // 128*128*65 cplx
  float2* imgT  = bufB + (size_t)DIMN*DIMN*KXN;         // 8*65*128 cplx
  float2* fpart = imgT + (size_t)NBATCH*KXN*DIMN;       // 8*128*65 cplx
  float*  mats  = (float*)(fpart + (size_t)NBATCH*DIMN*KXN); // 1000*12 f32
  float*  bestv = mats + 12000;                         // 1000 f32
  int*    besti = (int*)(bestv + 1000);                 // 1000 i32

  k_vol_fx<<<DIMN*DIMN, 128, 0, stream>>>(vol, bufA);
  k_vol_fy<<<DIMN*KXN, 128, 0, stream>>>(bufA, bufB);
  k_vol_fz<<<DIMN*KXN, 128, 0, stream>>>(bufB, bufA);   // bufA == vol_rfft
  k_img_fx<<<NBATCH*DIMN, 128, 0, stream>>>(imgs, imgT);
  k_img_fy<<<NBATCH*KXN, 128, 0, stream>>>(imgT, fpart);
  k_mats<<<4, 256, 0, stream>>>(rotm, mats);
  k_main<<<NBATCH*NOPT, 256, 0, stream>>>(bufA, fpart, ctfs, mats, bestv, besti);
  k_out<<<NBATCH, 64, 0, stream>>>(bestv, besti, mats, out);
}

// Round 4
// 241.975 us; speedup vs baseline: 1.7431x; 1.3111x over previous
//
#include <hip/hip_runtime.h>
#include <math.h>

#define DIMN 128
#define KXN  65
#define NBATCH 8
#define NOPT 125

// ============ wave-level 128-point FFT (radix-2 DIF, 2 points/lane) ==========
// Input: A = x[lane], B = x[lane+64] (natural order).
// Output: A = X[e], B = X[e+1], where e = bitrev7(lane) (even).
// X[k] = sum_n x[n] * exp(sigma*2*pi*i*n*k/128); twiddles precomputed per lane.
__device__ __forceinline__ void fft_twiddles(float sigma, int lane,
                                             float* twr, float* twi){
  const float W = 0.04908738521234052f;   // 2*pi/128
  float s, c;
  sincosf(sigma * W * (float)lane, &s, &c);
  twr[0] = c; twi[0] = s;
#pragma unroll
  for (int st = 1; st <= 6; ++st){
    int off = 64 >> st;
    int m = (lane & (off - 1)) << st;
    sincosf(sigma * W * (float)m, &s, &c);
    bool hi = (lane & off) != 0;
    twr[st] = hi ? c : 1.f;
    twi[st] = hi ? s : 0.f;
  }
}

__device__ __forceinline__ void wave_fft128(float& Ar, float& Ai, float& Br, float& Bi,
                                            const float* twr, const float* twi, int lane){
  {
    float dr = Ar - Br, di = Ai - Bi;
    Ar += Br; Ai += Bi;
    float nr = dr*twr[0] - di*twi[0];
    Bi = dr*twi[0] + di*twr[0];
    Br = nr;
  }
#pragma unroll
  for (int s = 1; s <= 6; ++s){
    int off = 64 >> s;
    float sgn = (lane & off) ? -1.f : 1.f;
    float pr = __shfl_xor(Ar, off, 64);
    float pi = __shfl_xor(Ai, off, 64);
    float dr = fmaf(Ar, sgn, pr);
    float di = fmaf(Ai, sgn, pi);
    Ar = dr*twr[s] - di*twi[s];
    Ai = dr*twi[s] + di*twr[s];
    pr = __shfl_xor(Br, off, 64);
    pi = __shfl_xor(Bi, off, 64);
    dr = fmaf(Br, sgn, pr);
    di = fmaf(Bi, sgn, pi);
    Br = dr*twr[s] - di*twi[s];
    Bi = dr*twi[s] + di*twr[s];
  }
}

// ---------------- Volume FFT pass 1: rfft over x, sign (-1)^k ----------------
// 2 real lines Hermitian-packed per wave. 4 waves/block -> 8 lines/block.
// out layout: A_T[(z*65+k)*128 + y]
__global__ __launch_bounds__(256) void k_vol_fx(const float* __restrict__ vol,
                                                float2* __restrict__ outT){
  __shared__ float2 Zbuf[4][128];
  int t = threadIdx.x, lane = t & 63, w = t >> 6;
  int l1 = blockIdx.x*8 + 2*w;      // line index z*128+y
  int l2 = l1 + 1;
  float twr[7], twi[7];
  fft_twiddles(-1.f, lane, twr, twi);
  float Ar = vol[l1*DIMN + lane],      Ai = vol[l2*DIMN + lane];
  float Br = vol[l1*DIMN + lane + 64], Bi = vol[l2*DIMN + lane + 64];
  wave_fft128(Ar, Ai, Br, Bi, twr, twi, lane);
  int e = (int)(__brev((unsigned)lane) >> 25);
  Zbuf[w][e]   = make_float2(Ar, Ai);
  Zbuf[w][e+1] = make_float2(Br, Bi);
  __syncthreads();
  int z = l1 >> 7, y1 = l1 & 127, y2 = y1 + 1;
  int k = lane, m = (128 - k) & 127;
  float2 zk = Zbuf[w][k], zm = Zbuf[w][m];
  float s = (k & 1) ? -0.5f : 0.5f;
  float2 X1 = make_float2(s*(zk.x + zm.x), s*(zk.y - zm.y));
  float2 X2 = make_float2(s*(zk.y + zm.y), s*(zm.x - zk.x));
  outT[(z*KXN + k)*DIMN + y1] = X1;
  outT[(z*KXN + k)*DIMN + y2] = X2;
  if (lane == 0){
    float2 z64 = Zbuf[w][64];
    outT[(z*KXN + 64)*DIMN + y1] = make_float2(z64.x, 0.f);
    outT[(z*KXN + 64)*DIMN + y2] = make_float2(z64.y, 0.f);
  }
}

// ---------------- Volume FFT pass 2: fft over y, shifted output, sign (-1)^f -
// in: A_T[(z*65+k)*128 + y]   out: B_T[(t*65+k)*128 + z], t=(f+64)&127
__global__ __launch_bounds__(256) void k_vol_fy(const float2* __restrict__ inT,
                                                float2* __restrict__ outT){
  int t = threadIdx.x, lane = t & 63, w = t >> 6;
  int col = blockIdx.x*4 + w;       // z*65 + k
  int z = col / 65, k = col - z*65;
  float twr[7], twi[7];
  fft_twiddles(-1.f, lane, twr, twi);
  const float2* base = inT + (size_t)col*DIMN;
  float2 A = base[lane], B = base[lane + 64];
  wave_fft128(A.x, A.y, B.x, B.y, twr, twi, lane);
  int e = (int)(__brev((unsigned)lane) >> 25);
  int pe = (e + 64) & 127;
  outT[(pe*KXN + k)*DIMN + z]     = A;                      // even f: sign +1
  outT[((pe+1)*KXN + k)*DIMN + z] = make_float2(-B.x, -B.y); // odd f: sign -1
}

// ---------------- Volume FFT pass 3: fft over z, shifted output, sign (-1)^f -
// in: B_T[(j*65+k)*128 + z]   out: volF[(t*128+j)*65 + k]
__global__ __launch_bounds__(256) void k_vol_fz(const float2* __restrict__ inT,
                                                float2* __restrict__ volF){
  int t = threadIdx.x, lane = t & 63, w = t >> 6;
  int col = blockIdx.x*4 + w;       // j*65 + k
  int j = col / 65, k = col - j*65;
  float twr[7], twi[7];
  fft_twiddles(-1.f, lane, twr, twi);
  const float2* base = inT + (size_t)col*DIMN;
  float2 A = base[lane], B = base[lane + 64];
  wave_fft128(A.x, A.y, B.x, B.y, twr, twi, lane);
  int e = (int)(__brev((unsigned)lane) >> 25);
  int pe = (e + 64) & 127;
  volF[((size_t)pe*DIMN + j)*KXN + k]     = A;
  volF[((size_t)(pe+1)*DIMN + j)*KXN + k] = make_float2(-B.x, -B.y);
}

// ---------------- Image FFT pass 1: mask + rfft over x, sign (-1)^k ----------
// out: AI_T[(b*65+k)*128 + y]
__global__ __launch_bounds__(256) void k_img_fx(const float* __restrict__ imgs,
                                                float2* __restrict__ outT){
  __shared__ float2 Zbuf[4][128];
  int t = threadIdx.x, lane = t & 63, w = t >> 6;
  int l1 = blockIdx.x*8 + 2*w;      // line index b*128+y
  int l2 = l1 + 1;
  int y1 = l1 & 127, y2 = y1 + 1;
  int dy1 = y1 - 64, dy2 = y2 - 64;
  int dxa = lane - 64, dxb = lane;  // x=lane, x=lane+64 -> dx=lane-64, lane
  float m1a = (dy1*dy1 + dxa*dxa <= 4096) ? 1.f : 0.f;
  float m1b = (dy1*dy1 + dxb*dxb <= 4096) ? 1.f : 0.f;
  float m2a = (dy2*dy2 + dxa*dxa <= 4096) ? 1.f : 0.f;
  float m2b = (dy2*dy2 + dxb*dxb <= 4096) ? 1.f : 0.f;
  float twr[7], twi[7];
  fft_twiddles(-1.f, lane, twr, twi);
  float Ar = imgs[l1*DIMN + lane]*m1a,      Ai = imgs[l2*DIMN + lane]*m2a;
  float Br = imgs[l1*DIMN + lane + 64]*m1b, Bi = imgs[l2*DIMN + lane + 64]*m2b;
  wave_fft128(Ar, Ai, Br, Bi, twr, twi, lane);
  int e = (int)(__brev((unsigned)lane) >> 25);
  Zbuf[w][e]   = make_float2(Ar, Ai);
  Zbuf[w][e+1] = make_float2(Br, Bi);
  __syncthreads();
  int b = l1 >> 7;
  int k = lane, m = (128 - k) & 127;
  float2 zk = Zbuf[w][k], zm = Zbuf[w][m];
  float s = (k & 1) ? -0.5f : 0.5f;
  float2 X1 = make_float2(s*(zk.x + zm.x), s*(zk.y - zm.y));
  float2 X2 = make_float2(s*(zk.y + zm.y), s*(zm.x - zk.x));
  outT[(b*KXN + k)*DIMN + y1] = X1;
  outT[(b*KXN + k)*DIMN + y2] = X2;
  if (lane == 0){
    float2 z64 = Zbuf[w][64];
    outT[(b*KXN + 64)*DIMN + y1] = make_float2(z64.x, 0.f);
    outT[(b*KXN + 64)*DIMN + y2] = make_float2(z64.y, 0.f);
  }
}

// ---------------- Image FFT pass 2: fft over y, shifted output, sign (-1)^f --
// in: AI_T[(b*65+k)*128 + y]   out: fparts[(b*128+t)*65 + k]
__global__ __launch_bounds__(256) void k_img_fy(const float2* __restrict__ inT,
                                                float2* __restrict__ fparts){
  int t = threadIdx.x, lane = t & 63, w = t >> 6;
  int col = blockIdx.x*4 + w;       // b*65 + k
  int b = col / 65, k = col - b*65;
  float twr[7], twi[7];
  fft_twiddles(-1.f, lane, twr, twi);
  const float2* base = inT + (size_t)col*DIMN;
  float2 A = base[lane], B = base[lane + 64];
  wave_fft128(A.x, A.y, B.x, B.y, twr, twi, lane);
  int e = (int)(__brev((unsigned)lane) >> 25);
  int pe = (e + 64) & 127;
  fparts[((size_t)b*DIMN + pe)*KXN + k]     = A;
  fparts[((size_t)b*DIMN + pe + 1)*KXN + k] = make_float2(-B.x, -B.y);
}

// ---------------- Per-(b,opt) rotation columns + expanded euler --------------
__global__ __launch_bounds__(256) void k_mats(const float* __restrict__ rotm,
                                              float* __restrict__ mats){
  int tid = blockIdx.x*blockDim.x + threadIdx.x;
  if (tid >= NBATCH*NOPT) return;
  int b = tid / NOPT, o = tid - b*NOPT;
  const float* R = rotm + b*9;
  float beta  = acosf(fminf(1.f, fmaxf(-1.f, R[8])));
  float alpha = atan2f(R[5], R[2]);
  float gamma = atan2f(R[7], -R[6]);
  const float DEG = 57.29577951308232f;
  float e0 = alpha*DEG + 3.0f*(float)(o/25      - 2);
  float e1 = beta *DEG + 3.0f*(float)((o/5) % 5 - 2);
  float e2 = gamma*DEG + 3.0f*(float)(o % 5     - 2);
  const float RAD = 0.017453292519943295f;
  float sa, ca, sb, cb, sc, cc;
  sincosf(e0*RAD, &sa, &ca);
  sincosf(e1*RAD, &sb, &cb);
  sincosf(e2*RAD, &sc, &cc);
  float* m = mats + tid*12;
  m[0] = sb*sc;
  m[1] = -sa*cb*sc + ca*cc;
  m[2] = -ca*cb*sc - sa*cc;
  m[3] = -sb*cc;
  m[4] = sa*cb*cc + ca*sc;
  m[5] = ca*cb*cc - sa*sc;
  m[6] = e0; m[7] = e1; m[8] = e2;
}

// ---- prod element: trilinear slice sample * ctf, then f * conj(P) -----------
__device__ __forceinline__ float2 prod_elem(int h, int kx,
                                            float c1z, float c1y, float c1x,
                                            float c2z, float c2y, float c2x,
                                            const float2* __restrict__ volF,
                                            const float2* __restrict__ fp,
                                            const float*  __restrict__ cf){
  float fyv = (float)(h - 64) * 0.0078125f;
  float fxv = (float)kx * 0.0078125f;
  float cz = fyv*c1z + fxv*c2z;
  float cy = fyv*c1y + fxv*c2y;
  float cx = fyv*c1x + fxv*c2x;
  bool cj = (cx < 0.f);
  if (cj){ cz = -cz; cy = -cy; cx = -cx; }
  float pz = cz*128.f + 64.f;
  float py = cy*128.f + 64.f;
  float px = cx*128.f;
  float fz = floorf(pz), fy = floorf(py), fx = floorf(px);
  int iz = (int)fz, iy = (int)fy, ix = (int)fx;
  float tz = pz - fz, ty = py - fy, tx = px - fx;
  float wz0 = ((unsigned)iz      < 128u) ? 1.f - tz : 0.f;
  float wz1 = ((unsigned)(iz+1)  < 128u) ? tz       : 0.f;
  float wy0 = ((unsigned)iy      < 128u) ? 1.f - ty : 0.f;
  float wy1 = ((unsigned)(iy+1)  < 128u) ? ty       : 0.f;
  float wx0 = ((unsigned)ix      < 65u)  ? 1.f - tx : 0.f;
  float wx1 = ((unsigned)(ix+1)  < 65u)  ? tx       : 0.f;
  int iz0 = min(max(iz,   0), 127), iz1 = min(max(iz+1, 0), 127);
  int iy0 = min(max(iy,   0), 127), iy1 = min(max(iy+1, 0), 127);
  int ix0 = min(max(ix,   0), 64),  ix1 = min(max(ix+1, 0), 64);
  const float2* r00 = volF + (size_t)(iz0*128 + iy0)*65;
  const float2* r01 = volF + (size_t)(iz0*128 + iy1)*65;
  const float2* r10 = volF + (size_t)(iz1*128 + iy0)*65;
  const float2* r11 = volF + (size_t)(iz1*128 + iy1)*65;
  float2 v000 = r00[ix0], v001 = r00[ix1];
  float2 v010 = r01[ix0], v011 = r01[ix1];
  float2 v100 = r10[ix0], v101 = r10[ix1];
  float2 v110 = r11[ix0], v111 = r11[ix1];
  float w00 = wz0*wy0, w01 = wz0*wy1, w10 = wz1*wy0, w11 = wz1*wy1;
  float ar = w00*(wx0*v000.x + wx1*v001.x) + w01*(wx0*v010.x + wx1*v011.x)
           + w10*(wx0*v100.x + wx1*v101.x) + w11*(wx0*v110.x + wx1*v111.x);
  float ai = w00*(wx0*v000.y + wx1*v001.y) + w01*(wx0*v010.y + wx1*v011.y)
           + w10*(wx0*v100.y + wx1*v101.y) + w11*(wx0*v110.y + wx1*v111.y);
  if (cj) ai = -ai;
  float ct = cf[h*KXN + kx];
  float Pr = ar*ct, Pi = ai*ct;
  float2 f = fp[h*KXN + kx];
  return make_float2(f.x*Pr + f.y*Pi, f.y*Pr - f.x*Pi);   // f * conj(P)
}

// ---------------- Main: slice + ctf + conj-mult + wave-FFT + argmax ----------
// 512 threads / 8 waves per block: 8 waves/SIMD latency hiding for the gathers.
__global__ __launch_bounds__(512, 8) void k_main(const float2* __restrict__ volF,
                                                 const float2* __restrict__ fparts,
                                                 const float* __restrict__ ctfs,
                                                 const float* __restrict__ mats,
                                                 float* __restrict__ bestv,
                                                 int* __restrict__ besti){
  __shared__ float2 Q[64*65];       // Q[s][kx], normalized, window rows only
  __shared__ float rvw[8];
  __shared__ int   riw[8];

  int t = threadIdx.x, lane = t & 63, g = t >> 6;   // g = 0..7
  int blk = blockIdx.x;             // b*125 + o
  int b = blk / NOPT;

  float twr[7], twi[7];
  fft_twiddles(1.f, lane, twr, twi);   // sign + (inverse direction), shared B&C

  const float* mp = mats + (size_t)blk*12;
  float c1z = mp[0], c1y = mp[1], c1x = mp[2];
  float c2z = mp[3], c2y = mp[4], c2x = mp[5];
  const float2* fp = fparts + (size_t)b*DIMN*KXN;
  const float*  cf = ctfs   + (size_t)b*DIMN*KXN;

  int e = (int)(__brev((unsigned)lane) >> 25);   // bitrev7(lane), even
  int slA = (e + 32) & 127;                      // window row for bin e
  bool inwin = (slA < 64);
  const float NRM = 6.103515625e-05f;            // 1/16384

  // ---- Phase A+B: prod columns -> FFT over h -> Q rows ----
#pragma unroll 1
  for (int ci = 0; ci < 9; ++ci){
    int kx = 8*ci + g;
    if (kx > 64) break;                          // wave-uniform
    float2 A = prod_elem(lane,      kx, c1z,c1y,c1x, c2z,c2y,c2x, volF, fp, cf);
    float2 B = prod_elem(lane + 64, kx, c1z,c1y,c1x, c2z,c2y,c2x, volF, fp, cf);
    wave_fft128(A.x, A.y, B.x, B.y, twr, twi, lane);
    if (inwin){
      Q[slA*KXN + kx]     = make_float2( A.x*NRM,  A.y*NRM);   // row slA   (even, +)
      Q[(slA+1)*KXN + kx] = make_float2(-B.x*NRM, -B.y*NRM);   // row slA+1 (odd,  -)
    }
  }
  __syncthreads();

  // ---- Phase C: 32 row-pair FFTs over kx (Hermitian-packed), fused argmax ----
  float bv = -INFINITY; int bi = 0;
  int ra = 64 - lane;                            // B-side source column (lane0 -> 64)
#pragma unroll 1
  for (int pi = 0; pi < 4; ++pi){
    int r1 = (4*g + pi) << 1;                    // rows r1, r1+1
    float2 a1 = Q[r1*KXN + lane];
    float2 a2 = Q[(r1+1)*KXN + lane];
    float2 b1 = Q[r1*KXN + ra];
    float2 b2 = Q[(r1+1)*KXN + ra];
    if (lane == 0){ a1.y = 0.f; a2.y = 0.f; b1.y = 0.f; b2.y = 0.f; }
    else { b1.y = -b1.y; b2.y = -b2.y; }         // conj for mirrored bins
    float zAr = a1.x - a2.y, zAi = a1.y + a2.x;  // z = x1 + i*x2
    float zBr = b1.x - b2.y, zBi = b1.y + b2.x;
    wave_fft128(zAr, zAi, zBr, zBi, twr, twi, lane);
    if (inwin){
      int i0 = (r1 << 6) + slA;                  // row r1, wx = slA
      if (zAr > bv || (zAr == bv && i0      < bi)){ bv = zAr; bi = i0; }
      if (zAi > bv || (zAi == bv && i0+64   < bi)){ bv = zAi; bi = i0+64; }
      if (zBr > bv || (zBr == bv && i0+1    < bi)){ bv = zBr; bi = i0+1; }
      if (zBi > bv || (zBi == bv && i0+65   < bi)){ bv = zBi; bi = i0+65; }
    }
  }

  // wave-level shuffle reduce (lowest index wins ties)
#pragma unroll
  for (int off = 32; off > 0; off >>= 1){
    float v2 = __shfl_down(bv, off, 64);
    int   i2 = __shfl_down(bi, off, 64);
    if (v2 > bv || (v2 == bv && i2 < bi)){ bv = v2; bi = i2; }
  }
  if (lane == 0){ rvw[g] = bv; riw[g] = bi; }
  __syncthreads();
  if (t == 0){
    float fv = rvw[0]; int fi = riw[0];
#pragma unroll
    for (int wv = 1; wv < 8; ++wv){
      float v2 = rvw[wv]; int i2 = riw[wv];
      if (v2 > fv || (v2 == fv && i2 < fi)){ fv = v2; fi = i2; }
    }
    bestv[blk] = fv; besti[blk] = fi;
  }
}

// ---------------- Final selection / outputs ----------------------------------
__global__ __launch_bounds__(64) void k_out(const float* __restrict__ bestv,
                                            const int* __restrict__ besti,
                                            const float* __restrict__ mats,
                                            float* __restrict__ out){
  int b = blockIdx.x;
  if (threadIdx.x != 0) return;
  float bv = -INFINITY; int bo = 0;
  for (int o = 0; o < NOPT; ++o){
    float v = bestv[b*NOPT + o];
    if (v > bv){ bv = v; bo = o; }
  }
  float sum = 0.f;
  for (int o = 0; o < NOPT; ++o) sum += bestv[b*NOPT + o];
  float mean = sum * (1.0f/125.0f);
  float ss = 0.f;
  for (int o = 0; o < NOPT; ++o){
    float d = bestv[b*NOPT + o] - mean;
    ss += d*d;
  }
  float stdv = sqrtf(ss * (1.0f/124.0f));

  int wi = besti[b*NOPT + bo];
  int row = (wi >> 6) + 32;
  int col = (wi & 63) + 32;

  out[b] = bv;
  const float* mm = mats + (size_t)(b*NOPT + bo)*12;
  const float RAD = 0.017453292519943295f;
  float sa, ca, sb, cb, sc, cc;
  sincosf(mm[6]*RAD, &sa, &ca);
  sincosf(mm[7]*RAD, &sb, &cb);
  sincosf(mm[8]*RAD, &sc, &cc);
  float* R = out + 8 + b*9;
  R[0] = ca*cb*cc - sa*sc;  R[1] = -ca*cb*sc - sa*cc;  R[2] = ca*sb;
  R[3] = sa*cb*cc + ca*sc;  R[4] = -sa*cb*sc + ca*cc;  R[5] = sa*sb;
  R[6] = -sb*cc;            R[7] = sb*sc;              R[8] = cb;
  out[80 + b*2 + 0] = -((float)col - 64.f) * 1.5f;
  out[80 + b*2 + 1] = -((float)row - 64.f) * 1.5f;
  float z = (bv - mean) / ((stdv + 1e-6f) * 1.4142135623730951f);
  out[96 + b] = 0.5f*(1.f + erff(z));
}

extern "C" void kernel_launch(void* const* d_in, const int* in_sizes, int n_in,
                              void* d_out, int out_size, void* d_ws, size_t ws_size,
                              hipStream_t stream){
  (void)in_sizes; (void)n_in; (void)out_size; (void)ws_size;
  const float* vol  = (const float*)d_in[0];
  const float* imgs = (const float*)d_in[1];
  const float* ctfs = (const float*)d_in[2];
  const float* rotm = (const float*)d_in[3];
  float* out = (float*)d_out;

  float2* bufA  = (float2*)d_ws;                        // 128*128*65 cplx
  float2* bufB  = bufA + (size_t)DIMN*DIMN*KXN;         // 128*128*65 cplx
  float2* imgT  = bufB + (size_t)DIMN*DIMN*KXN;         // 8*65*128 cplx
  float2* fpart = imgT + (size_t)NBATCH*KXN*DIMN;       // 8*128*65 cplx
  float*  mats  = (float*)(fpart + (size_t)NBATCH*DIMN*KXN); // 1000*12 f32
  float*  bestv = mats + 12000;                         // 1000 f32
  int*    besti = (int*)(bestv + 1000);                 // 1000 i32

  k_vol_fx<<<(DIMN*DIMN)/8, 256, 0, stream>>>(vol, bufA);
  k_vol_fy<<<(DIMN*KXN)/4, 256, 0, stream>>>(bufA, bufB);
  k_vol_fz<<<(DIMN*KXN)/4, 256, 0, stream>>>(bufB, bufA);   // bufA == vol_rfft
  k_img_fx<<<(NBATCH*DIMN)/8, 256, 0, stream>>>(imgs, imgT);
  k_img_fy<<<(NBATCH*KXN)/4, 256, 0, stream>>>(imgT, fpart);
  k_mats<<<4, 256, 0, stream>>>(rotm, mats);
  k_main<<<NBATCH*NOPT, 512, 0, stream>>>(bufA, fpart, ctfs, mats, bestv, besti);
  k_out<<<NBATCH, 64, 0, stream>>>(bestv, besti, mats, out);
}

// Round 5
// 224.357 us; speedup vs baseline: 1.8799x; 1.0785x over previous
//
#include <hip/hip_runtime.h>
#include <math.h>

#define DIMN 128
#define KXN  65
#define NBATCH 8
#define NOPT 125

// ============ wave-level 128-point FFT (radix-2 DIF, 2 points/lane) ==========
// Input: A = x[lane], B = x[lane+64] (natural order).
// Output: A = X[e], B = X[e+1], where e = bitrev7(lane) (even).
// X[k] = sum_n x[n] * exp(sigma*2*pi*i*n*k/128); twiddles precomputed per lane.
__device__ __forceinline__ void fft_twiddles(float sigma, int lane,
                                             float* twr, float* twi){
  const float W = 0.04908738521234052f;   // 2*pi/128
  float s, c;
  sincosf(sigma * W * (float)lane, &s, &c);
  twr[0] = c; twi[0] = s;
#pragma unroll
  for (int st = 1; st <= 6; ++st){
    int off = 64 >> st;
    int m = (lane & (off - 1)) << st;
    sincosf(sigma * W * (float)m, &s, &c);
    bool hi = (lane & off) != 0;
    twr[st] = hi ? c : 1.f;
    twi[st] = hi ? s : 0.f;
  }
}

__device__ __forceinline__ void wave_fft128(float& Ar, float& Ai, float& Br, float& Bi,
                                            const float* twr, const float* twi, int lane){
  {
    float dr = Ar - Br, di = Ai - Bi;
    Ar += Br; Ai += Bi;
    float nr = dr*twr[0] - di*twi[0];
    Bi = dr*twi[0] + di*twr[0];
    Br = nr;
  }
#pragma unroll
  for (int s = 1; s <= 6; ++s){
    int off = 64 >> s;
    float sgn = (lane & off) ? -1.f : 1.f;
    float pr = __shfl_xor(Ar, off, 64);
    float pi = __shfl_xor(Ai, off, 64);
    float dr = fmaf(Ar, sgn, pr);
    float di = fmaf(Ai, sgn, pi);
    Ar = dr*twr[s] - di*twi[s];
    Ai = dr*twi[s] + di*twr[s];
    pr = __shfl_xor(Br, off, 64);
    pi = __shfl_xor(Bi, off, 64);
    dr = fmaf(Br, sgn, pr);
    di = fmaf(Bi, sgn, pi);
    Br = dr*twr[s] - di*twi[s];
    Bi = dr*twi[s] + di*twr[s];
  }
}

// ---------------- Volume FFT pass 1: rfft over x, sign (-1)^k ----------------
// 2 real lines Hermitian-packed per wave. 4 waves/block -> 8 lines/block.
// out layout: A_T[(z*65+k)*128 + y]
__global__ __launch_bounds__(256) void k_vol_fx(const float* __restrict__ vol,
                                                float2* __restrict__ outT){
  __shared__ float2 Zbuf[4][128];
  int t = threadIdx.x, lane = t & 63, w = t >> 6;
  int l1 = blockIdx.x*8 + 2*w;      // line index z*128+y
  int l2 = l1 + 1;
  float twr[7], twi[7];
  fft_twiddles(-1.f, lane, twr, twi);
  float Ar = vol[l1*DIMN + lane],      Ai = vol[l2*DIMN + lane];
  float Br = vol[l1*DIMN + lane + 64], Bi = vol[l2*DIMN + lane + 64];
  wave_fft128(Ar, Ai, Br, Bi, twr, twi, lane);
  int e = (int)(__brev((unsigned)lane) >> 25);
  Zbuf[w][e]   = make_float2(Ar, Ai);
  Zbuf[w][e+1] = make_float2(Br, Bi);
  __syncthreads();
  int z = l1 >> 7, y1 = l1 & 127, y2 = y1 + 1;
  int k = lane, m = (128 - k) & 127;
  float2 zk = Zbuf[w][k], zm = Zbuf[w][m];
  float s = (k & 1) ? -0.5f : 0.5f;
  float2 X1 = make_float2(s*(zk.x + zm.x), s*(zk.y - zm.y));
  float2 X2 = make_float2(s*(zk.y + zm.y), s*(zm.x - zk.x));
  outT[(z*KXN + k)*DIMN + y1] = X1;
  outT[(z*KXN + k)*DIMN + y2] = X2;
  if (lane == 0){
    float2 z64 = Zbuf[w][64];
    outT[(z*KXN + 64)*DIMN + y1] = make_float2(z64.x, 0.f);
    outT[(z*KXN + 64)*DIMN + y2] = make_float2(z64.y, 0.f);
  }
}

// ---------------- Volume FFT pass 2: fft over y, shifted output, sign (-1)^f -
// in: A_T[(z*65+k)*128 + y]   out: B_T[(t*65+k)*128 + z], t=(f+64)&127
__global__ __launch_bounds__(256) void k_vol_fy(const float2* __restrict__ inT,
                                                float2* __restrict__ outT){
  int t = threadIdx.x, lane = t & 63, w = t >> 6;
  int col = blockIdx.x*4 + w;       // z*65 + k
  int z = col / 65, k = col - z*65;
  float twr[7], twi[7];
  fft_twiddles(-1.f, lane, twr, twi);
  const float2* base = inT + (size_t)col*DIMN;
  float2 A = base[lane], B = base[lane + 64];
  wave_fft128(A.x, A.y, B.x, B.y, twr, twi, lane);
  int e = (int)(__brev((unsigned)lane) >> 25);
  int pe = (e + 64) & 127;
  outT[(pe*KXN + k)*DIMN + z]     = A;                      // even f: sign +1
  outT[((pe+1)*KXN + k)*DIMN + z] = make_float2(-B.x, -B.y); // odd f: sign -1
}

// ---------------- Volume FFT pass 3: fft over z, shifted output, sign (-1)^f -
// in: B_T[(j*65+k)*128 + z]   out: volF[(t*128+j)*65 + k]
__global__ __launch_bounds__(256) void k_vol_fz(const float2* __restrict__ inT,
                                                float2* __restrict__ volF){
  int t = threadIdx.x, lane = t & 63, w = t >> 6;
  int col = blockIdx.x*4 + w;       // j*65 + k
  int j = col / 65, k = col - j*65;
  float twr[7], twi[7];
  fft_twiddles(-1.f, lane, twr, twi);
  const float2* base = inT + (size_t)col*DIMN;
  float2 A = base[lane], B = base[lane + 64];
  wave_fft128(A.x, A.y, B.x, B.y, twr, twi, lane);
  int e = (int)(__brev((unsigned)lane) >> 25);
  int pe = (e + 64) & 127;
  volF[((size_t)pe*DIMN + j)*KXN + k]     = A;
  volF[((size_t)(pe+1)*DIMN + j)*KXN + k] = make_float2(-B.x, -B.y);
}

// ---------------- Fat-texel build: FAT[z][y][x][8] = 2x2x2 neighborhood ------
// One entry = 8 float2 = 64 B, 64B-aligned -> one cache line per trilinear tap.
// q = zs*4 + ys*2 + xs, neighbors clamped.
__global__ __launch_bounds__(256) void k_fat(const float2* __restrict__ volF,
                                             float2* __restrict__ FAT){
  int idx = blockIdx.x*256 + threadIdx.x;        // over 128*128*65 = 256*4160
  int x = idx % 65; int zy = idx / 65; int y = zy & 127; int z = zy >> 7;
  int z1 = min(z+1,127), y1 = min(y+1,127), x1 = min(x+1,64);
  const size_t s00 = ((size_t)z *128 + y )*65;
  const size_t s01 = ((size_t)z *128 + y1)*65;
  const size_t s10 = ((size_t)z1*128 + y )*65;
  const size_t s11 = ((size_t)z1*128 + y1)*65;
  float2* o = FAT + ((size_t)idx << 3);
  o[0] = volF[s00+x]; o[1] = volF[s00+x1];
  o[2] = volF[s01+x]; o[3] = volF[s01+x1];
  o[4] = volF[s10+x]; o[5] = volF[s10+x1];
  o[6] = volF[s11+x]; o[7] = volF[s11+x1];
}

// ---------------- Image FFT pass 1: mask + rfft over x, sign (-1)^k ----------
// out: AI_T[(b*65+k)*128 + y]
__global__ __launch_bounds__(256) void k_img_fx(const float* __restrict__ imgs,
                                                float2* __restrict__ outT){
  __shared__ float2 Zbuf[4][128];
  int t = threadIdx.x, lane = t & 63, w = t >> 6;
  int l1 = blockIdx.x*8 + 2*w;      // line index b*128+y
  int l2 = l1 + 1;
  int y1 = l1 & 127, y2 = y1 + 1;
  int dy1 = y1 - 64, dy2 = y2 - 64;
  int dxa = lane - 64, dxb = lane;  // x=lane, x=lane+64 -> dx=lane-64, lane
  float m1a = (dy1*dy1 + dxa*dxa <= 4096) ? 1.f : 0.f;
  float m1b = (dy1*dy1 + dxb*dxb <= 4096) ? 1.f : 0.f;
  float m2a = (dy2*dy2 + dxa*dxa <= 4096) ? 1.f : 0.f;
  float m2b = (dy2*dy2 + dxb*dxb <= 4096) ? 1.f : 0.f;
  float twr[7], twi[7];
  fft_twiddles(-1.f, lane, twr, twi);
  float Ar = imgs[l1*DIMN + lane]*m1a,      Ai = imgs[l2*DIMN + lane]*m2a;
  float Br = imgs[l1*DIMN + lane + 64]*m1b, Bi = imgs[l2*DIMN + lane + 64]*m2b;
  wave_fft128(Ar, Ai, Br, Bi, twr, twi, lane);
  int e = (int)(__brev((unsigned)lane) >> 25);
  Zbuf[w][e]   = make_float2(Ar, Ai);
  Zbuf[w][e+1] = make_float2(Br, Bi);
  __syncthreads();
  int b = l1 >> 7;
  int k = lane, m = (128 - k) & 127;
  float2 zk = Zbuf[w][k], zm = Zbuf[w][m];
  float s = (k & 1) ? -0.5f : 0.5f;
  float2 X1 = make_float2(s*(zk.x + zm.x), s*(zk.y - zm.y));
  float2 X2 = make_float2(s*(zk.y + zm.y), s*(zm.x - zk.x));
  outT[(b*KXN + k)*DIMN + y1] = X1;
  outT[(b*KXN + k)*DIMN + y2] = X2;
  if (lane == 0){
    float2 z64 = Zbuf[w][64];
    outT[(b*KXN + 64)*DIMN + y1] = make_float2(z64.x, 0.f);
    outT[(b*KXN + 64)*DIMN + y2] = make_float2(z64.y, 0.f);
  }
}

// ---------------- Image FFT pass 2: fft over y, shifted output, sign (-1)^f --
// in: AI_T[(b*65+k)*128 + y]   out: fparts[(b*128+t)*65 + k]
__global__ __launch_bounds__(256) void k_img_fy(const float2* __restrict__ inT,
                                                float2* __restrict__ fparts){
  int t = threadIdx.x, lane = t & 63, w = t >> 6;
  int col = blockIdx.x*4 + w;       // b*65 + k
  int b = col / 65, k = col - b*65;
  float twr[7], twi[7];
  fft_twiddles(-1.f, lane, twr, twi);
  const float2* base = inT + (size_t)col*DIMN;
  float2 A = base[lane], B = base[lane + 64];
  wave_fft128(A.x, A.y, B.x, B.y, twr, twi, lane);
  int e = (int)(__brev((unsigned)lane) >> 25);
  int pe = (e + 64) & 127;
  fparts[((size_t)b*DIMN + pe)*KXN + k]     = A;
  fparts[((size_t)b*DIMN + pe + 1)*KXN + k] = make_float2(-B.x, -B.y);
}

// ---------------- Per-(b,opt) rotation columns + expanded euler --------------
__global__ __launch_bounds__(256) void k_mats(const float* __restrict__ rotm,
                                              float* __restrict__ mats){
  int tid = blockIdx.x*blockDim.x + threadIdx.x;
  if (tid >= NBATCH*NOPT) return;
  int b = tid / NOPT, o = tid - b*NOPT;
  const float* R = rotm + b*9;
  float beta  = acosf(fminf(1.f, fmaxf(-1.f, R[8])));
  float alpha = atan2f(R[5], R[2]);
  float gamma = atan2f(R[7], -R[6]);
  const float DEG = 57.29577951308232f;
  float e0 = alpha*DEG + 3.0f*(float)(o/25      - 2);
  float e1 = beta *DEG + 3.0f*(float)((o/5) % 5 - 2);
  float e2 = gamma*DEG + 3.0f*(float)(o % 5     - 2);
  const float RAD = 0.017453292519943295f;
  float sa, ca, sb, cb, sc, cc;
  sincosf(e0*RAD, &sa, &ca);
  sincosf(e1*RAD, &sb, &cb);
  sincosf(e2*RAD, &sc, &cc);
  float* m = mats + tid*12;
  m[0] = sb*sc;
  m[1] = -sa*cb*sc + ca*cc;
  m[2] = -ca*cb*sc - sa*cc;
  m[3] = -sb*cc;
  m[4] = sa*cb*cc + ca*sc;
  m[5] = ca*cb*cc - sa*sc;
  m[6] = e0; m[7] = e1; m[8] = e2;
}

// ---- prod element: fat-texel trilinear sample * ctf, then f * conj(P) -------
__device__ __forceinline__ float2 prod_elem(int h, int kx,
                                            float c1z, float c1y, float c1x,
                                            float c2z, float c2y, float c2x,
                                            const float2* __restrict__ FAT,
                                            const float2* __restrict__ fp,
                                            const float*  __restrict__ cf){
  float fyv = (float)(h - 64) * 0.0078125f;
  float fxv = (float)kx * 0.0078125f;
  float cz = fyv*c1z + fxv*c2z;
  float cy = fyv*c1y + fxv*c2y;
  float cx = fyv*c1x + fxv*c2x;
  bool cj = (cx < 0.f);
  if (cj){ cz = -cz; cy = -cy; cx = -cx; }
  float pz = cz*128.f + 64.f;
  float py = cy*128.f + 64.f;
  float px = cx*128.f;
  float fz = floorf(pz), fy = floorf(py), fx = floorf(px);
  int iz = (int)fz, iy = (int)fy, ix = (int)fx;
  float tz = pz - fz, ty = py - fy, tx = px - fx;
  // effective weights vs clamped base (out-of-range taps zeroed; base-1 case
  // shifts weight t onto the low slot)
  float wz0 = ((unsigned)iz < 128u) ? 1.f - tz : ((iz == -1) ? tz : 0.f);
  float wz1 = ((unsigned)iz < 127u) ? tz : 0.f;
  float wy0 = ((unsigned)iy < 128u) ? 1.f - ty : ((iy == -1) ? ty : 0.f);
  float wy1 = ((unsigned)iy < 127u) ? ty : 0.f;
  float wx0 = ((unsigned)ix < 65u)  ? 1.f - tx : ((ix == -1) ? tx : 0.f);
  float wx1 = ((unsigned)ix < 64u)  ? tx : 0.f;
  int bz = min(max(iz, 0), 127), by = min(max(iy, 0), 127), bx = min(max(ix, 0), 64);
  const float4* F = (const float4*)(FAT + ((((size_t)bz*128 + by)*65 + bx) << 3));
  float4 f0 = F[0], f1 = F[1], f2 = F[2], f3 = F[3];
  float w00 = wz0*wy0, w01 = wz0*wy1, w10 = wz1*wy0, w11 = wz1*wy1;
  float ar = w00*(wx0*f0.x + wx1*f0.z) + w01*(wx0*f1.x + wx1*f1.z)
           + w10*(wx0*f2.x + wx1*f2.z) + w11*(wx0*f3.x + wx1*f3.z);
  float ai = w00*(wx0*f0.y + wx1*f0.w) + w01*(wx0*f1.y + wx1*f1.w)
           + w10*(wx0*f2.y + wx1*f2.w) + w11*(wx0*f3.y + wx1*f3.w);
  if (cj) ai = -ai;
  float ct = cf[h*KXN + kx];
  float Pr = ar*ct, Pi = ai*ct;
  float2 f = fp[h*KXN + kx];
  return make_float2(f.x*Pr + f.y*Pi, f.y*Pr - f.x*Pi);   // f * conj(P)
}

// ---------------- Main: slice + ctf + conj-mult + wave-FFT + argmax ----------
// 512 threads / 8 waves per block.
__global__ __launch_bounds__(512, 8) void k_main(const float2* __restrict__ FAT,
                                                 const float2* __restrict__ fparts,
                                                 const float* __restrict__ ctfs,
                                                 const float* __restrict__ mats,
                                                 float* __restrict__ bestv,
                                                 int* __restrict__ besti){
  __shared__ float2 Q[64*65];       // Q[s][kx], normalized, window rows only
  __shared__ float rvw[8];
  __shared__ int   riw[8];

  int t = threadIdx.x, lane = t & 63, g = t >> 6;   // g = 0..7
  int blk = blockIdx.x;             // b*125 + o
  int b = blk / NOPT;

  float twr[7], twi[7];
  fft_twiddles(1.f, lane, twr, twi);   // sign + (inverse direction), shared B&C

  const float* mp = mats + (size_t)blk*12;
  float c1z = mp[0], c1y = mp[1], c1x = mp[2];
  float c2z = mp[3], c2y = mp[4], c2x = mp[5];
  const float2* fp = fparts + (size_t)b*DIMN*KXN;
  const float*  cf = ctfs   + (size_t)b*DIMN*KXN;

  int e = (int)(__brev((unsigned)lane) >> 25);   // bitrev7(lane), even
  int slA = (e + 32) & 127;                      // window row for bin e
  bool inwin = (slA < 64);
  const float NRM = 6.103515625e-05f;            // 1/16384

  // ---- Phase A+B: prod columns -> FFT over h -> Q rows ----
#pragma unroll 1
  for (int ci = 0; ci < 9; ++ci){
    int kx = 8*ci + g;
    if (kx > 64) break;                          // wave-uniform
    float2 A = prod_elem(lane,      kx, c1z,c1y,c1x, c2z,c2y,c2x, FAT, fp, cf);
    float2 B = prod_elem(lane + 64, kx, c1z,c1y,c1x, c2z,c2y,c2x, FAT, fp, cf);
    wave_fft128(A.x, A.y, B.x, B.y, twr, twi, lane);
    if (inwin){
      Q[slA*KXN + kx]     = make_float2( A.x*NRM,  A.y*NRM);   // row slA   (even, +)
      Q[(slA+1)*KXN + kx] = make_float2(-B.x*NRM, -B.y*NRM);   // row slA+1 (odd,  -)
    }
  }
  __syncthreads();

  // ---- Phase C: 32 row-pair FFTs over kx (Hermitian-packed), fused argmax ----
  float bv = -INFINITY; int bi = 0;
  int ra = 64 - lane;                            // B-side source column (lane0 -> 64)
#pragma unroll 1
  for (int pi = 0; pi < 4; ++pi){
    int r1 = (4*g + pi) << 1;                    // rows r1, r1+1
    float2 a1 = Q[r1*KXN + lane];
    float2 a2 = Q[(r1+1)*KXN + lane];
    float2 b1 = Q[r1*KXN + ra];
    float2 b2 = Q[(r1+1)*KXN + ra];
    if (lane == 0){ a1.y = 0.f; a2.y = 0.f; b1.y = 0.f; b2.y = 0.f; }
    else { b1.y = -b1.y; b2.y = -b2.y; }         // conj for mirrored bins
    float zAr = a1.x - a2.y, zAi = a1.y + a2.x;  // z = x1 + i*x2
    float zBr = b1.x - b2.y, zBi = b1.y + b2.x;
    wave_fft128(zAr, zAi, zBr, zBi, twr, twi, lane);
    if (inwin){
      int i0 = (r1 << 6) + slA;                  // row r1, wx = slA
      if (zAr > bv || (zAr == bv && i0      < bi)){ bv = zAr; bi = i0; }
      if (zAi > bv || (zAi == bv && i0+64   < bi)){ bv = zAi; bi = i0+64; }
      if (zBr > bv || (zBr == bv && i0+1    < bi)){ bv = zBr; bi = i0+1; }
      if (zBi > bv || (zBi == bv && i0+65   < bi)){ bv = zBi; bi = i0+65; }
    }
  }

  // wave-level shuffle reduce (lowest index wins ties)
#pragma unroll
  for (int off = 32; off > 0; off >>= 1){
    float v2 = __shfl_down(bv, off, 64);
    int   i2 = __shfl_down(bi, off, 64);
    if (v2 > bv || (v2 == bv && i2 < bi)){ bv = v2; bi = i2; }
  }
  if (lane == 0){ rvw[g] = bv; riw[g] = bi; }
  __syncthreads();
  if (t == 0){
    float fv = rvw[0]; int fi = riw[0];
#pragma unroll
    for (int wv = 1; wv < 8; ++wv){
      float v2 = rvw[wv]; int i2 = riw[wv];
      if (v2 > fv || (v2 == fv && i2 < fi)){ fv = v2; fi = i2; }
    }
    bestv[blk] = fv; besti[blk] = fi;
  }
}

// ---------------- Final selection / outputs ----------------------------------
__global__ __launch_bounds__(64) void k_out(const float* __restrict__ bestv,
                                            const int* __restrict__ besti,
                                            const float* __restrict__ mats,
                                            float* __restrict__ out){
  int b = blockIdx.x;
  if (threadIdx.x != 0) return;
  float bv = -INFINITY; int bo = 0;
  for (int o = 0; o < NOPT; ++o){
    float v = bestv[b*NOPT + o];
    if (v > bv){ bv = v; bo = o; }
  }
  float sum = 0.f;
  for (int o = 0; o < NOPT; ++o) sum += bestv[b*NOPT + o];
  float mean = sum * (1.0f/125.0f);
  float ss = 0.f;
  for (int o = 0; o < NOPT; ++o){
    float d = bestv[b*NOPT + o] - mean;
    ss += d*d;
  }
  float stdv = sqrtf(ss * (1.0f/124.0f));

  int wi = besti[b*NOPT + bo];
  int row = (wi >> 6) + 32;
  int col = (wi & 63) + 32;

  out[b] = bv;
  const float* mm = mats + (size_t)(b*NOPT + bo)*12;
  const float RAD = 0.017453292519943295f;
  float sa, ca, sb, cb, sc, cc;
  sincosf(mm[6]*RAD, &sa, &ca);
  sincosf(mm[7]*RAD, &sb, &cb);
  sincosf(mm[8]*RAD, &sc, &cc);
  float* R = out + 8 + b*9;
  R[0] = ca*cb*cc - sa*sc;  R[1] = -ca*cb*sc - sa*cc;  R[2] = ca*sb;
  R[3] = sa*cb*cc + ca*sc;  R[4] = -sa*cb*sc + ca*cc;  R[5] = sa*sb;
  R[6] = -sb*cc;            R[7] = sb*sc;              R[8] = cb;
  out[80 + b*2 + 0] = -((float)col - 64.f) * 1.5f;
  out[80 + b*2 + 1] = -((float)row - 64.f) * 1.5f;
  float z = (bv - mean) / ((stdv + 1e-6f) * 1.4142135623730951f);
  out[96 + b] = 0.5f*(1.f + erff(z));
}

extern "C" void kernel_launch(void* const* d_in, const int* in_sizes, int n_in,
                              void* d_out, int out_size, void* d_ws, size_t ws_size,
                              hipStream_t stream){
  (void)in_sizes; (void)n_in; (void)out_size; (void)ws_size;
  const float* vol  = (const float*)d_in[0];
  const float* imgs = (const float*)d_in[1];
  const float* ctfs = (const float*)d_in[2];
  const float* rotm = (const float*)d_in[3];
  float* out = (float*)d_out;

  // ws layout: FAT first (64B-aligned), then the FFT/work buffers.
  float2* FAT   = (float2*)d_ws;                        // 128*128*65*8 cplx = 68 MB
  float2* bufA  = FAT  + ((size_t)DIMN*DIMN*KXN*8);     // 128*128*65 cplx
  float2* bufB  = bufA + (size_t)DIMN*DIMN*KXN;         // 128*128*65 cplx
  float2* imgT  = bufB + (size_t)DIMN*DIMN*KXN;         // 8*65*128 cplx
  float2* fpart = imgT + (size_t)NBATCH*KXN*DIMN;       // 8*128*65 cplx
  float*  mats  = (float*)(fpart + (size_t)NBATCH*DIMN*KXN); // 1000*12 f32
  float*  bestv = mats + 12000;                         // 1000 f32
  int*    besti = (int*)(bestv + 1000);                 // 1000 i32

  k_vol_fx<<<(DIMN*DIMN)/8, 256, 0, stream>>>(vol, bufA);
  k_vol_fy<<<(DIMN*KXN)/4, 256, 0, stream>>>(bufA, bufB);
  k_vol_fz<<<(DIMN*KXN)/4, 256, 0, stream>>>(bufB, bufA);   // bufA == vol_rfft
  k_fat<<<(DIMN*DIMN*KXN)/256, 256, 0, stream>>>(bufA, FAT);
  k_img_fx<<<(NBATCH*DIMN)/8, 256, 0, stream>>>(imgs, imgT);
  k_img_fy<<<(NBATCH*KXN)/4, 256, 0, stream>>>(imgT, fpart);
  k_mats<<<4, 256, 0, stream>>>(rotm, mats);
  k_main<<<NBATCH*NOPT, 512, 0, stream>>>(FAT, fpart, ctfs, mats, bestv, besti);
  k_out<<<NBATCH, 64, 0, stream>>>(bestv, besti, mats, out);
}

// Round 6
// 166.319 us; speedup vs baseline: 2.5360x; 1.3490x over previous
//
#include <hip/hip_runtime.h>
#include <math.h>

#define DIMN 128
#define KXN  65
#define NBATCH 8
#define NOPT 125

// ============ wave-level 128-point FFT (radix-2 DIF, 2 points/lane) ==========
// Input: A = x[lane], B = x[lane+64] (natural order).
// Output: A = X[e], B = X[e+1], where e = bitrev7(lane) (even).
// X[k] = sum_n x[n] * exp(sigma*2*pi*i*n*k/128); twiddles precomputed per lane.
__device__ __forceinline__ void fft_twiddles(float sigma, int lane,
                                             float* twr, float* twi){
  const float W = 0.04908738521234052f;   // 2*pi/128
  float s, c;
  sincosf(sigma * W * (float)lane, &s, &c);
  twr[0] = c; twi[0] = s;
#pragma unroll
  for (int st = 1; st <= 6; ++st){
    int off = 64 >> st;
    int m = (lane & (off - 1)) << st;
    sincosf(sigma * W * (float)m, &s, &c);
    bool hi = (lane & off) != 0;
    twr[st] = hi ? c : 1.f;
    twi[st] = hi ? s : 0.f;
  }
}

__device__ __forceinline__ void wave_fft128(float& Ar, float& Ai, float& Br, float& Bi,
                                            const float* twr, const float* twi, int lane){
  {
    float dr = Ar - Br, di = Ai - Bi;
    Ar += Br; Ai += Bi;
    float nr = dr*twr[0] - di*twi[0];
    Bi = dr*twi[0] + di*twr[0];
    Br = nr;
  }
#pragma unroll
  for (int s = 1; s <= 6; ++s){
    int off = 64 >> s;
    float sgn = (lane & off) ? -1.f : 1.f;
    float pr = __shfl_xor(Ar, off, 64);
    float pi = __shfl_xor(Ai, off, 64);
    float dr = fmaf(Ar, sgn, pr);
    float di = fmaf(Ai, sgn, pi);
    Ar = dr*twr[s] - di*twi[s];
    Ai = dr*twi[s] + di*twr[s];
    pr = __shfl_xor(Br, off, 64);
    pi = __shfl_xor(Bi, off, 64);
    dr = fmaf(Br, sgn, pr);
    di = fmaf(Bi, sgn, pi);
    Br = dr*twr[s] - di*twi[s];
    Bi = dr*twi[s] + di*twr[s];
  }
}

// ---------------- Volume FFT pass 1: rfft over x, sign (-1)^k ----------------
// 2 real lines Hermitian-packed per wave. 4 waves/block -> 8 lines/block.
// out layout: A_T[(z*65+k)*128 + y]
__global__ __launch_bounds__(256) void k_vol_fx(const float* __restrict__ vol,
                                                float2* __restrict__ outT){
  __shared__ float2 Zbuf[4][128];
  int t = threadIdx.x, lane = t & 63, w = t >> 6;
  int l1 = blockIdx.x*8 + 2*w;      // line index z*128+y
  int l2 = l1 + 1;
  float twr[7], twi[7];
  fft_twiddles(-1.f, lane, twr, twi);
  float Ar = vol[l1*DIMN + lane],      Ai = vol[l2*DIMN + lane];
  float Br = vol[l1*DIMN + lane + 64], Bi = vol[l2*DIMN + lane + 64];
  wave_fft128(Ar, Ai, Br, Bi, twr, twi, lane);
  int e = (int)(__brev((unsigned)lane) >> 25);
  Zbuf[w][e]   = make_float2(Ar, Ai);
  Zbuf[w][e+1] = make_float2(Br, Bi);
  __syncthreads();
  int z = l1 >> 7, y1 = l1 & 127, y2 = y1 + 1;
  int k = lane, m = (128 - k) & 127;
  float2 zk = Zbuf[w][k], zm = Zbuf[w][m];
  float s = (k & 1) ? -0.5f : 0.5f;
  float2 X1 = make_float2(s*(zk.x + zm.x), s*(zk.y - zm.y));
  float2 X2 = make_float2(s*(zk.y + zm.y), s*(zm.x - zk.x));
  outT[(z*KXN + k)*DIMN + y1] = X1;
  outT[(z*KXN + k)*DIMN + y2] = X2;
  if (lane == 0){
    float2 z64 = Zbuf[w][64];
    outT[(z*KXN + 64)*DIMN + y1] = make_float2(z64.x, 0.f);
    outT[(z*KXN + 64)*DIMN + y2] = make_float2(z64.y, 0.f);
  }
}

// ---------------- Volume FFT pass 2: fft over y, shifted output, sign (-1)^f -
// in: A_T[(z*65+k)*128 + y]   out: B_T[(t*65+k)*128 + z], t=(f+64)&127
__global__ __launch_bounds__(256) void k_vol_fy(const float2* __restrict__ inT,
                                                float2* __restrict__ outT){
  int t = threadIdx.x, lane = t & 63, w = t >> 6;
  int col = blockIdx.x*4 + w;       // z*65 + k
  int z = col / 65, k = col - z*65;
  float twr[7], twi[7];
  fft_twiddles(-1.f, lane, twr, twi);
  const float2* base = inT + (size_t)col*DIMN;
  float2 A = base[lane], B = base[lane + 64];
  wave_fft128(A.x, A.y, B.x, B.y, twr, twi, lane);
  int e = (int)(__brev((unsigned)lane) >> 25);
  int pe = (e + 64) & 127;
  outT[(pe*KXN + k)*DIMN + z]     = A;                      // even f: sign +1
  outT[((pe+1)*KXN + k)*DIMN + z] = make_float2(-B.x, -B.y); // odd f: sign -1
}

// ---------------- Volume FFT pass 3: fft over z, shifted output, sign (-1)^f -
// in: B_T[(j*65+k)*128 + z]   out: volF[(t*128+j)*65 + k]
__global__ __launch_bounds__(256) void k_vol_fz(const float2* __restrict__ inT,
                                                float2* __restrict__ volF){
  int t = threadIdx.x, lane = t & 63, w = t >> 6;
  int col = blockIdx.x*4 + w;       // j*65 + k
  int j = col / 65, k = col - j*65;
  float twr[7], twi[7];
  fft_twiddles(-1.f, lane, twr, twi);
  const float2* base = inT + (size_t)col*DIMN;
  float2 A = base[lane], B = base[lane + 64];
  wave_fft128(A.x, A.y, B.x, B.y, twr, twi, lane);
  int e = (int)(__brev((unsigned)lane) >> 25);
  int pe = (e + 64) & 127;
  volF[((size_t)pe*DIMN + j)*KXN + k]     = A;
  volF[((size_t)(pe+1)*DIMN + j)*KXN + k] = make_float2(-B.x, -B.y);
}

// ---------------- Fat-texel build: FAT[z][y][x][8] = 2x2x2 neighborhood ------
// One entry = 8 float2 = 64 B, 64B-aligned -> one cache line per trilinear tap.
__global__ __launch_bounds__(256) void k_fat(const float2* __restrict__ volF,
                                             float2* __restrict__ FAT){
  int idx = blockIdx.x*256 + threadIdx.x;        // over 128*128*65 = 256*4160
  int x = idx % 65; int zy = idx / 65; int y = zy & 127; int z = zy >> 7;
  int z1 = min(z+1,127), y1 = min(y+1,127), x1 = min(x+1,64);
  const size_t s00 = ((size_t)z *128 + y )*65;
  const size_t s01 = ((size_t)z *128 + y1)*65;
  const size_t s10 = ((size_t)z1*128 + y )*65;
  const size_t s11 = ((size_t)z1*128 + y1)*65;
  float2 a0 = volF[s00+x], a1 = volF[s00+x1];
  float2 b0 = volF[s01+x], b1 = volF[s01+x1];
  float2 c0 = volF[s10+x], c1 = volF[s10+x1];
  float2 d0 = volF[s11+x], d1 = volF[s11+x1];
  float4* o = (float4*)(FAT + ((size_t)idx << 3));
  o[0] = make_float4(a0.x, a0.y, a1.x, a1.y);
  o[1] = make_float4(b0.x, b0.y, b1.x, b1.y);
  o[2] = make_float4(c0.x, c0.y, c1.x, c1.y);
  o[3] = make_float4(d0.x, d0.y, d1.x, d1.y);
}

// ---------------- Image FFT pass 1: mask + rfft over x, sign (-1)^k ----------
// out: AI_T[(b*65+k)*128 + y]
__global__ __launch_bounds__(256) void k_img_fx(const float* __restrict__ imgs,
                                                float2* __restrict__ outT){
  __shared__ float2 Zbuf[4][128];
  int t = threadIdx.x, lane = t & 63, w = t >> 6;
  int l1 = blockIdx.x*8 + 2*w;      // line index b*128+y
  int l2 = l1 + 1;
  int y1 = l1 & 127, y2 = y1 + 1;
  int dy1 = y1 - 64, dy2 = y2 - 64;
  int dxa = lane - 64, dxb = lane;  // x=lane, x=lane+64 -> dx=lane-64, lane
  float m1a = (dy1*dy1 + dxa*dxa <= 4096) ? 1.f : 0.f;
  float m1b = (dy1*dy1 + dxb*dxb <= 4096) ? 1.f : 0.f;
  float m2a = (dy2*dy2 + dxa*dxa <= 4096) ? 1.f : 0.f;
  float m2b = (dy2*dy2 + dxb*dxb <= 4096) ? 1.f : 0.f;
  float twr[7], twi[7];
  fft_twiddles(-1.f, lane, twr, twi);
  float Ar = imgs[l1*DIMN + lane]*m1a,      Ai = imgs[l2*DIMN + lane]*m2a;
  float Br = imgs[l1*DIMN + lane + 64]*m1b, Bi = imgs[l2*DIMN + lane + 64]*m2b;
  wave_fft128(Ar, Ai, Br, Bi, twr, twi, lane);
  int e = (int)(__brev((unsigned)lane) >> 25);
  Zbuf[w][e]   = make_float2(Ar, Ai);
  Zbuf[w][e+1] = make_float2(Br, Bi);
  __syncthreads();
  int b = l1 >> 7;
  int k = lane, m = (128 - k) & 127;
  float2 zk = Zbuf[w][k], zm = Zbuf[w][m];
  float s = (k & 1) ? -0.5f : 0.5f;
  float2 X1 = make_float2(s*(zk.x + zm.x), s*(zk.y - zm.y));
  float2 X2 = make_float2(s*(zk.y + zm.y), s*(zm.x - zk.x));
  outT[(b*KXN + k)*DIMN + y1] = X1;
  outT[(b*KXN + k)*DIMN + y2] = X2;
  if (lane == 0){
    float2 z64 = Zbuf[w][64];
    outT[(b*KXN + 64)*DIMN + y1] = make_float2(z64.x, 0.f);
    outT[(b*KXN + 64)*DIMN + y2] = make_float2(z64.y, 0.f);
  }
}

// ---------------- Image FFT pass 2: fft over y -> TRANSPOSED fparts ----------
// in: AI_T[(b*65+k)*128 + y]   out: fpT[(b*65+k)*128 + t] (t = shifted row)
__global__ __launch_bounds__(256) void k_img_fy(const float2* __restrict__ inT,
                                                float2* __restrict__ fpT){
  int t = threadIdx.x, lane = t & 63, w = t >> 6;
  int col = blockIdx.x*4 + w;       // b*65 + k
  float twr[7], twi[7];
  fft_twiddles(-1.f, lane, twr, twi);
  const float2* base = inT + (size_t)col*DIMN;
  float2 A = base[lane], B = base[lane + 64];
  wave_fft128(A.x, A.y, B.x, B.y, twr, twi, lane);
  int e = (int)(__brev((unsigned)lane) >> 25);
  int pe = (e + 64) & 127;
  float2* obase = fpT + (size_t)col*DIMN;
  obase[pe]     = A;
  obase[pe + 1] = make_float2(-B.x, -B.y);
}

// ---------------- CTF transpose: cfT[(b*65+x)*128 + y] = ctfs[(b*128+y)*65+x]
__global__ __launch_bounds__(256) void k_ctfT(const float* __restrict__ ctfs,
                                              float* __restrict__ cfT){
  int idx = blockIdx.x*256 + threadIdx.x;        // over 8*128*65 = 66560 = 260*256
  int x = idx % 65; int by = idx / 65; int y = by & 127; int b = by >> 7;
  cfT[((size_t)b*KXN + x)*DIMN + y] = ctfs[idx];
}

// ---------------- Per-(b,opt) rotation columns + expanded euler --------------
__global__ __launch_bounds__(256) void k_mats(const float* __restrict__ rotm,
                                              float* __restrict__ mats){
  int tid = blockIdx.x*blockDim.x + threadIdx.x;
  if (tid >= NBATCH*NOPT) return;
  int b = tid / NOPT, o = tid - b*NOPT;
  const float* R = rotm + b*9;
  float beta  = acosf(fminf(1.f, fmaxf(-1.f, R[8])));
  float alpha = atan2f(R[5], R[2]);
  float gamma = atan2f(R[7], -R[6]);
  const float DEG = 57.29577951308232f;
  float e0 = alpha*DEG + 3.0f*(float)(o/25      - 2);
  float e1 = beta *DEG + 3.0f*(float)((o/5) % 5 - 2);
  float e2 = gamma*DEG + 3.0f*(float)(o % 5     - 2);
  const float RAD = 0.017453292519943295f;
  float sa, ca, sb, cb, sc, cc;
  sincosf(e0*RAD, &sa, &ca);
  sincosf(e1*RAD, &sb, &cb);
  sincosf(e2*RAD, &sc, &cc);
  float* m = mats + tid*12;
  m[0] = sb*sc;
  m[1] = -sa*cb*sc + ca*cc;
  m[2] = -ca*cb*sc - sa*cc;
  m[3] = -sb*cc;
  m[4] = sa*cb*cc + ca*sc;
  m[5] = ca*cb*cc - sa*sc;
  m[6] = e0; m[7] = e1; m[8] = e2;
}

// ---- prod element: fat-texel trilinear sample * ctf, then f * conj(P) -------
// fpc/cfc are the kx-column bases (transposed layouts), indexed by h.
__device__ __forceinline__ float2 prod_elem(int h, int kx,
                                            float c1z, float c1y, float c1x,
                                            float c2z, float c2y, float c2x,
                                            const float2* __restrict__ FAT,
                                            const float2* __restrict__ fpc,
                                            const float*  __restrict__ cfc){
  float fyv = (float)(h - 64) * 0.0078125f;
  float fxv = (float)kx * 0.0078125f;
  float cz = fyv*c1z + fxv*c2z;
  float cy = fyv*c1y + fxv*c2y;
  float cx = fyv*c1x + fxv*c2x;
  bool cj = (cx < 0.f);
  if (cj){ cz = -cz; cy = -cy; cx = -cx; }
  float pz = cz*128.f + 64.f;
  float py = cy*128.f + 64.f;
  float px = cx*128.f;
  float fz = floorf(pz), fy = floorf(py), fx = floorf(px);
  int iz = (int)fz, iy = (int)fy, ix = (int)fx;
  float tz = pz - fz, ty = py - fy, tx = px - fx;
  float wz0 = ((unsigned)iz < 128u) ? 1.f - tz : ((iz == -1) ? tz : 0.f);
  float wz1 = ((unsigned)iz < 127u) ? tz : 0.f;
  float wy0 = ((unsigned)iy < 128u) ? 1.f - ty : ((iy == -1) ? ty : 0.f);
  float wy1 = ((unsigned)iy < 127u) ? ty : 0.f;
  float wx0 = ((unsigned)ix < 65u)  ? 1.f - tx : ((ix == -1) ? tx : 0.f);
  float wx1 = ((unsigned)ix < 64u)  ? tx : 0.f;
  int bz = min(max(iz, 0), 127), by = min(max(iy, 0), 127), bx = min(max(ix, 0), 64);
  const float4* F = (const float4*)(FAT + ((((size_t)bz*128 + by)*65 + bx) << 3));
  float4 f0 = F[0], f1 = F[1], f2 = F[2], f3 = F[3];
  float w00 = wz0*wy0, w01 = wz0*wy1, w10 = wz1*wy0, w11 = wz1*wy1;
  float ar = w00*(wx0*f0.x + wx1*f0.z) + w01*(wx0*f1.x + wx1*f1.z)
           + w10*(wx0*f2.x + wx1*f2.z) + w11*(wx0*f3.x + wx1*f3.z);
  float ai = w00*(wx0*f0.y + wx1*f0.w) + w01*(wx0*f1.y + wx1*f1.w)
           + w10*(wx0*f2.y + wx1*f2.w) + w11*(wx0*f3.y + wx1*f3.w);
  if (cj) ai = -ai;
  float ct = cfc[h];
  float Pr = ar*ct, Pi = ai*ct;
  float2 f = fpc[h];
  return make_float2(f.x*Pr + f.y*Pi, f.y*Pr - f.x*Pi);   // f * conj(P)
}

// ---------------- Main: slice + ctf + conj-mult + wave-FFT + argmax ----------
// 512 threads / 8 waves per block. XCD-pinned: b = blk & 7 so each batch's 125
// option-blocks co-reside on one XCD and share the slice slab through its L2.
__global__ __launch_bounds__(512, 8) void k_main(const float2* __restrict__ FAT,
                                                 const float2* __restrict__ fpT,
                                                 const float* __restrict__ cfT,
                                                 const float* __restrict__ mats,
                                                 float* __restrict__ bestv,
                                                 int* __restrict__ besti){
  __shared__ float2 Q[64*65];       // Q[s][kx], normalized, window rows only
  __shared__ float rvw[8];
  __shared__ int   riw[8];

  int t = threadIdx.x, lane = t & 63, g = t >> 6;   // g = 0..7
  int blk = blockIdx.x;
  int b = blk & 7;                  // XCD-pinned batch
  int o = blk >> 3;                 // option

  float twr[7], twi[7];
  fft_twiddles(1.f, lane, twr, twi);   // sign + (inverse direction), shared B&C

  const float* mp = mats + (size_t)(b*NOPT + o)*12;
  float c1z = mp[0], c1y = mp[1], c1x = mp[2];
  float c2z = mp[3], c2y = mp[4], c2x = mp[5];
  const float2* fp = fpT + (size_t)b*KXN*DIMN;
  const float*  cf = cfT + (size_t)b*KXN*DIMN;

  int e = (int)(__brev((unsigned)lane) >> 25);   // bitrev7(lane), even
  int slA = (e + 32) & 127;                      // window row for bin e
  bool inwin = (slA < 64);
  const float NRM = 6.103515625e-05f;            // 1/16384

  // ---- Phase A+B: prod columns -> FFT over h -> Q rows ----
#pragma unroll 1
  for (int ci = 0; ci < 9; ++ci){
    int kx = 8*ci + g;
    if (kx > 64) break;                          // wave-uniform
    const float2* fpc = fp + (size_t)kx*DIMN;
    const float*  cfc = cf + (size_t)kx*DIMN;
    float2 A = prod_elem(lane,      kx, c1z,c1y,c1x, c2z,c2y,c2x, FAT, fpc, cfc);
    float2 B = prod_elem(lane + 64, kx, c1z,c1y,c1x, c2z,c2y,c2x, FAT, fpc, cfc);
    wave_fft128(A.x, A.y, B.x, B.y, twr, twi, lane);
    if (inwin){
      Q[slA*KXN + kx]     = make_float2( A.x*NRM,  A.y*NRM);   // row slA   (even, +)
      Q[(slA+1)*KXN + kx] = make_float2(-B.x*NRM, -B.y*NRM);   // row slA+1 (odd,  -)
    }
  }
  __syncthreads();

  // ---- Phase C: 32 row-pair FFTs over kx (Hermitian-packed), fused argmax ----
  float bv = -INFINITY; int bi = 0;
  int ra = 64 - lane;                            // B-side source column (lane0 -> 64)
#pragma unroll 1
  for (int pi = 0; pi < 4; ++pi){
    int r1 = (4*g + pi) << 1;                    // rows r1, r1+1
    float2 a1 = Q[r1*KXN + lane];
    float2 a2 = Q[(r1+1)*KXN + lane];
    float2 b1 = Q[r1*KXN + ra];
    float2 b2 = Q[(r1+1)*KXN + ra];
    if (lane == 0){ a1.y = 0.f; a2.y = 0.f; b1.y = 0.f; b2.y = 0.f; }
    else { b1.y = -b1.y; b2.y = -b2.y; }         // conj for mirrored bins
    float zAr = a1.x - a2.y, zAi = a1.y + a2.x;  // z = x1 + i*x2
    float zBr = b1.x - b2.y, zBi = b1.y + b2.x;
    wave_fft128(zAr, zAi, zBr, zBi, twr, twi, lane);
    if (inwin){
      int i0 = (r1 << 6) + slA;                  // row r1, wx = slA
      if (zAr > bv || (zAr == bv && i0      < bi)){ bv = zAr; bi = i0; }
      if (zAi > bv || (zAi == bv && i0+64   < bi)){ bv = zAi; bi = i0+64; }
      if (zBr > bv || (zBr == bv && i0+1    < bi)){ bv = zBr; bi = i0+1; }
      if (zBi > bv || (zBi == bv && i0+65   < bi)){ bv = zBi; bi = i0+65; }
    }
  }

  // wave-level shuffle reduce (lowest index wins ties)
#pragma unroll
  for (int off = 32; off > 0; off >>= 1){
    float v2 = __shfl_down(bv, off, 64);
    int   i2 = __shfl_down(bi, off, 64);
    if (v2 > bv || (v2 == bv && i2 < bi)){ bv = v2; bi = i2; }
  }
  if (lane == 0){ rvw[g] = bv; riw[g] = bi; }
  __syncthreads();
  if (t == 0){
    float fv = rvw[0]; int fi = riw[0];
#pragma unroll
    for (int wv = 1; wv < 8; ++wv){
      float v2 = rvw[wv]; int i2 = riw[wv];
      if (v2 > fv || (v2 == fv && i2 < fi)){ fv = v2; fi = i2; }
    }
    bestv[b*NOPT + o] = fv; besti[b*NOPT + o] = fi;
  }
}

// ---------------- Final selection / outputs ----------------------------------
__global__ __launch_bounds__(64) void k_out(const float* __restrict__ bestv,
                                            const int* __restrict__ besti,
                                            const float* __restrict__ mats,
                                            float* __restrict__ out){
  int b = blockIdx.x;
  if (threadIdx.x != 0) return;
  float bv = -INFINITY; int bo = 0;
  for (int o = 0; o < NOPT; ++o){
    float v = bestv[b*NOPT + o];
    if (v > bv){ bv = v; bo = o; }
  }
  float sum = 0.f;
  for (int o = 0; o < NOPT; ++o) sum += bestv[b*NOPT + o];
  float mean = sum * (1.0f/125.0f);
  float ss = 0.f;
  for (int o = 0; o < NOPT; ++o){
    float d = bestv[b*NOPT + o] - mean;
    ss += d*d;
  }
  float stdv = sqrtf(ss * (1.0f/124.0f));

  int wi = besti[b*NOPT + bo];
  int row = (wi >> 6) + 32;
  int col = (wi & 63) + 32;

  out[b] = bv;
  const float* mm = mats + (size_t)(b*NOPT + bo)*12;
  const float RAD = 0.017453292519943295f;
  float sa, ca, sb, cb, sc, cc;
  sincosf(mm[6]*RAD, &sa, &ca);
  sincosf(mm[7]*RAD, &sb, &cb);
  sincosf(mm[8]*RAD, &sc, &cc);
  float* R = out + 8 + b*9;
  R[0] = ca*cb*cc - sa*sc;  R[1] = -ca*cb*sc - sa*cc;  R[2] = ca*sb;
  R[3] = sa*cb*cc + ca*sc;  R[4] = -sa*cb*sc + ca*cc;  R[5] = sa*sb;
  R[6] = -sb*cc;            R[7] = sb*sc;              R[8] = cb;
  out[80 + b*2 + 0] = -((float)col - 64.f) * 1.5f;
  out[80 + b*2 + 1] = -((float)row - 64.f) * 1.5f;
  float z = (bv - mean) / ((stdv + 1e-6f) * 1.4142135623730951f);
  out[96 + b] = 0.5f*(1.f + erff(z));
}

extern "C" void kernel_launch(void* const* d_in, const int* in_sizes, int n_in,
                              void* d_out, int out_size, void* d_ws, size_t ws_size,
                              hipStream_t stream){
  (void)in_sizes; (void)n_in; (void)out_size; (void)ws_size;
  const float* vol  = (const float*)d_in[0];
  const float* imgs = (const float*)d_in[1];
  const float* ctfs = (const float*)d_in[2];
  const float* rotm = (const float*)d_in[3];
  float* out = (float*)d_out;

  // ws layout: FAT first (64B-aligned), then the FFT/work buffers.
  float2* FAT   = (float2*)d_ws;                        // 128*128*65*8 cplx = 68 MB
  float2* bufA  = FAT  + ((size_t)DIMN*DIMN*KXN*8);     // 128*128*65 cplx
  float2* bufB  = bufA + (size_t)DIMN*DIMN*KXN;         // 128*128*65 cplx
  float2* imgT  = bufB + (size_t)DIMN*DIMN*KXN;         // 8*65*128 cplx
  float2* fpT   = imgT + (size_t)NBATCH*KXN*DIMN;       // 8*65*128 cplx (transposed)
  float*  cfT   = (float*)(fpT + (size_t)NBATCH*KXN*DIMN);   // 8*65*128 f32
  float*  mats  = cfT + (size_t)NBATCH*KXN*DIMN;        // 1000*12 f32
  float*  bestv = mats + 12000;                         // 1000 f32
  int*    besti = (int*)(bestv + 1000);                 // 1000 i32

  k_vol_fx<<<(DIMN*DIMN)/8, 256, 0, stream>>>(vol, bufA);
  k_vol_fy<<<(DIMN*KXN)/4, 256, 0, stream>>>(bufA, bufB);
  k_vol_fz<<<(DIMN*KXN)/4, 256, 0, stream>>>(bufB, bufA);   // bufA == vol_rfft
  k_fat<<<(DIMN*DIMN*KXN)/256, 256, 0, stream>>>(bufA, FAT);
  k_img_fx<<<(NBATCH*DIMN)/8, 256, 0, stream>>>(imgs, imgT);
  k_img_fy<<<(NBATCH*KXN)/4, 256, 0, stream>>>(imgT, fpT);
  k_ctfT<<<(NBATCH*DIMN*KXN)/256, 256, 0, stream>>>(ctfs, cfT);
  k_mats<<<4, 256, 0, stream>>>(rotm, mats);
  k_main<<<NBATCH*NOPT, 512, 0, stream>>>(FAT, fpT, cfT, mats, bestv, besti);
  k_out<<<NBATCH, 64, 0, stream>>>(bestv, besti, mats, out);
}

// Round 7
// 164.228 us; speedup vs baseline: 2.5683x; 1.0127x over previous
//
#include <hip/hip_runtime.h>
#include <math.h>

#define DIMN 128
#define KXN  65
#define NBATCH 8
#define NOPT 125

// ============ wave-level 128-point FFT (radix-2 DIF, 2 points/lane) ==========
// Input: A = x[lane], B = x[lane+64] (natural order).
// Output: A = X[e], B = X[e+1], where e = bitrev7(lane) (even).
__device__ __forceinline__ void fft_twiddles(float sigma, int lane,
                                             float* twr, float* twi){
  const float W = 0.04908738521234052f;   // 2*pi/128
  float s, c;
  sincosf(sigma * W * (float)lane, &s, &c);
  twr[0] = c; twi[0] = s;
#pragma unroll
  for (int st = 1; st <= 6; ++st){
    int off = 64 >> st;
    int m = (lane & (off - 1)) << st;
    sincosf(sigma * W * (float)m, &s, &c);
    bool hi = (lane & off) != 0;
    twr[st] = hi ? c : 1.f;
    twi[st] = hi ? s : 0.f;
  }
}

__device__ __forceinline__ void wave_fft128(float& Ar, float& Ai, float& Br, float& Bi,
                                            const float* twr, const float* twi, int lane){
  {
    float dr = Ar - Br, di = Ai - Bi;
    Ar += Br; Ai += Bi;
    float nr = dr*twr[0] - di*twi[0];
    Bi = dr*twi[0] + di*twr[0];
    Br = nr;
  }
#pragma unroll
  for (int s = 1; s <= 6; ++s){
    int off = 64 >> s;
    float sgn = (lane & off) ? -1.f : 1.f;
    float pr = __shfl_xor(Ar, off, 64);
    float pi = __shfl_xor(Ai, off, 64);
    float dr = fmaf(Ar, sgn, pr);
    float di = fmaf(Ai, sgn, pi);
    Ar = dr*twr[s] - di*twi[s];
    Ai = dr*twi[s] + di*twr[s];
    pr = __shfl_xor(Br, off, 64);
    pi = __shfl_xor(Bi, off, 64);
    dr = fmaf(Br, sgn, pr);
    di = fmaf(Bi, sgn, pi);
    Br = dr*twr[s] - di*twi[s];
    Bi = dr*twi[s] + di*twr[s];
  }
}

__device__ __forceinline__ int bitrev7(int lane){
  return (int)(__brev((unsigned)lane) >> 25);
}

// ======================= Launch 1: fx passes + ctfT + mats ===================
// bid <2048: vol_fx (8 lines)  | <2176: img_fx | <2436: ctfT | <2440: mats
// fx passes: 4 waves x 2 Hermitian-packed real lines; coalesced 64B row writes.
__global__ __launch_bounds__(256) void k_pre1(const float* __restrict__ vol,
                                              const float* __restrict__ imgs,
                                              const float* __restrict__ ctfs,
                                              const float* __restrict__ rotm,
                                              float2* __restrict__ A_T,
                                              float2* __restrict__ AI_T,
                                              float* __restrict__ cfT,
                                              float* __restrict__ mats){
  __shared__ float2 Zbuf[4][128];
  __shared__ float Xr[65][9];
  __shared__ float Xi[65][9];
  int bid = blockIdx.x;
  int t = threadIdx.x, lane = t & 63, w = t >> 6;

  if (bid < 2176){
    bool isimg = (bid >= 2048);
    const float* src = isimg ? imgs : vol;
    float2* dst = isimg ? AI_T : A_T;
    int l0 = (isimg ? (bid - 2048) : bid) * 8;   // 8 lines, same slab/image
    int l1 = l0 + 2*w, l2 = l1 + 1;
    float m1a = 1.f, m1b = 1.f, m2a = 1.f, m2b = 1.f;
    if (isimg){
      int y1 = l1 & 127, y2 = y1 + 1;
      int dy1 = y1 - 64, dy2 = y2 - 64;
      int dxa = lane - 64, dxb = lane;
      m1a = (dy1*dy1 + dxa*dxa <= 4096) ? 1.f : 0.f;
      m1b = (dy1*dy1 + dxb*dxb <= 4096) ? 1.f : 0.f;
      m2a = (dy2*dy2 + dxa*dxa <= 4096) ? 1.f : 0.f;
      m2b = (dy2*dy2 + dxb*dxb <= 4096) ? 1.f : 0.f;
    }
    float twr[7], twi[7];
    fft_twiddles(-1.f, lane, twr, twi);
    float Ar = src[l1*DIMN + lane]*m1a,      Ai = src[l2*DIMN + lane]*m2a;
    float Br = src[l1*DIMN + lane + 64]*m1b, Bi = src[l2*DIMN + lane + 64]*m2b;
    wave_fft128(Ar, Ai, Br, Bi, twr, twi, lane);
    int e = bitrev7(lane);
    Zbuf[w][e]   = make_float2(Ar, Ai);
    Zbuf[w][e+1] = make_float2(Br, Bi);
    __syncthreads();
    // Hermitian unpack: lane k, lines ly1=2w, ly2=2w+1
    {
      int k = lane, m = (128 - k) & 127;
      float2 zk = Zbuf[w][k], zm = Zbuf[w][m];
      float s = (k & 1) ? -0.5f : 0.5f;
      int ly1 = 2*w, ly2 = ly1 + 1;
      Xr[k][ly1] = s*(zk.x + zm.x);  Xi[k][ly1] = s*(zk.y - zm.y);
      Xr[k][ly2] = s*(zk.y + zm.y);  Xi[k][ly2] = s*(zm.x - zk.x);
      if (lane == 0){
        float2 z64 = Zbuf[w][64];
        Xr[64][ly1] = z64.x; Xi[64][ly1] = 0.f;
        Xr[64][ly2] = z64.y; Xi[64][ly2] = 0.f;
      }
    }
    __syncthreads();
    // coalesced write: dst[(slab*65+k)*128 + y0 + yo], 64 B per k-row
    int slab = l0 >> 7, y0 = l0 & 127;
    int kk = t >> 2, yo = (t & 3) * 2;
    float4 v = make_float4(Xr[kk][yo], Xi[kk][yo], Xr[kk][yo+1], Xi[kk][yo+1]);
    *(float4*)(dst + (size_t)(slab*KXN + kk)*DIMN + y0 + yo) = v;
    if (t < 4){
      int yo2 = t*2;
      float4 v2 = make_float4(Xr[64][yo2], Xi[64][yo2], Xr[64][yo2+1], Xi[64][yo2+1]);
      *(float4*)(dst + (size_t)(slab*KXN + 64)*DIMN + y0 + yo2) = v2;
    }
  } else if (bid < 2436){
    int idx = (bid - 2176)*256 + t;              // over 8*128*65 = 66560
    int x = idx % 65; int by = idx / 65; int y = by & 127; int b = by >> 7;
    cfT[((size_t)b*KXN + x)*DIMN + y] = ctfs[idx];
  } else {
    int tid = (bid - 2436)*256 + t;
    if (tid < NBATCH*NOPT){
      int b = tid / NOPT, o = tid - b*NOPT;
      const float* R = rotm + b*9;
      float beta  = acosf(fminf(1.f, fmaxf(-1.f, R[8])));
      float alpha = atan2f(R[5], R[2]);
      float gamma = atan2f(R[7], -R[6]);
      const float DEG = 57.29577951308232f;
      float e0 = alpha*DEG + 3.0f*(float)(o/25      - 2);
      float e1 = beta *DEG + 3.0f*(float)((o/5) % 5 - 2);
      float e2 = gamma*DEG + 3.0f*(float)(o % 5     - 2);
      const float RAD = 0.017453292519943295f;
      float sa, ca, sb, cb, sc, cc;
      sincosf(e0*RAD, &sa, &ca);
      sincosf(e1*RAD, &sb, &cb);
      sincosf(e2*RAD, &sc, &cc);
      float* m = mats + tid*12;
      m[0] = sb*sc;
      m[1] = -sa*cb*sc + ca*cc;
      m[2] = -ca*cb*sc - sa*cc;
      m[3] = -sb*cc;
      m[4] = sa*cb*cc + ca*sc;
      m[5] = ca*cb*cc - sa*sc;
      m[6] = e0; m[7] = e1; m[8] = e2;
    }
  }
}

// ======================= Launch 2: fy passes (vol + img) =====================
// bid <1040: vol_fy  k=bid>>4, z0=(bid&15)*8 ; else img_fy c0=(bid-1040)*8.
// 8 waves = 8 columns; SoA LDS by bin-pair p=e>>1; coalesced output writes.
__global__ __launch_bounds__(512) void k_pre2(const float2* __restrict__ A_T,
                                              const float2* __restrict__ AI_T,
                                              float2* __restrict__ B_T,
                                              float2* __restrict__ fpT){
  __shared__ float As[64][9], Ai_[64][9], Bs[64][9], Bi_[64][9];
  int bid = blockIdx.x;
  int t = threadIdx.x, lane = t & 63, w = t >> 6;
  float twr[7], twi[7];
  fft_twiddles(-1.f, lane, twr, twi);

  if (bid < 1040){
    int k = bid >> 4, z0 = (bid & 15) * 8;
    int col = (z0 + w)*KXN + k;
    const float2* base = A_T + (size_t)col*DIMN;
    float2 A = base[lane], B = base[lane + 64];
    wave_fft128(A.x, A.y, B.x, B.y, twr, twi, lane);
    int p = bitrev7(lane) >> 1;
    As[p][w] = A.x; Ai_[p][w] = A.y; Bs[p][w] = B.x; Bi_[p][w] = B.y;
    __syncthreads();
    int q = t >> 2, zo = (t & 3) * 2;
    int p2 = (((q & 126) + 64) & 127) >> 1;
    float4 v;
    if (q & 1) v = make_float4(-Bs[p2][zo], -Bi_[p2][zo], -Bs[p2][zo+1], -Bi_[p2][zo+1]);
    else       v = make_float4( As[p2][zo],  Ai_[p2][zo],  As[p2][zo+1],  Ai_[p2][zo+1]);
    *(float4*)(B_T + (size_t)(q*KXN + k)*DIMN + z0 + zo) = v;
  } else {
    int c0 = (bid - 1040) * 8;
    int col = c0 + w;                            // b*65 + k
    const float2* base = AI_T + (size_t)col*DIMN;
    float2 A = base[lane], B = base[lane + 64];
    wave_fft128(A.x, A.y, B.x, B.y, twr, twi, lane);
    int p = bitrev7(lane) >> 1;
    As[p][w] = A.x; Ai_[p][w] = A.y; Bs[p][w] = B.x; Bi_[p][w] = B.y;
    __syncthreads();
    int c = t >> 6, qo = (t & 63) * 2;
    int p2 = ((qo + 64) & 127) >> 1;
    float4 v = make_float4(As[p2][c], Ai_[p2][c], -Bs[p2][c], -Bi_[p2][c]);
    *(float4*)(fpT + (size_t)(c0 + c)*DIMN + qo) = v;
  }
}

// ======================= Launch 3: vol fz pass ===============================
// bid: j=bid/9, grp=bid%9, k0=grp*8, valid width vw (last group = 1).
__global__ __launch_bounds__(512) void k_fz(const float2* __restrict__ B_T,
                                            float2* __restrict__ volF){
  __shared__ float As[64][9], Ai_[64][9], Bs[64][9], Bi_[64][9];
  int bid = blockIdx.x;
  int j = bid / 9, grp = bid - j*9;
  int k0 = grp * 8;
  int vw = (grp == 8) ? 1 : 8;
  int t = threadIdx.x, lane = t & 63, w = t >> 6;
  if (w < vw){
    float twr[7], twi[7];
    fft_twiddles(-1.f, lane, twr, twi);
    int col = j*KXN + k0 + w;
    const float2* base = B_T + (size_t)col*DIMN;
    float2 A = base[lane], B = base[lane + 64];
    wave_fft128(A.x, A.y, B.x, B.y, twr, twi, lane);
    int p = bitrev7(lane) >> 1;
    As[p][w] = A.x; Ai_[p][w] = A.y; Bs[p][w] = B.x; Bi_[p][w] = B.y;
  }
  __syncthreads();
  int q = t >> 2, ko = (t & 3) * 2;
  int p2 = (((q & 126) + 64) & 127) >> 1;
  float2* obase = volF + (size_t)(q*DIMN + j)*KXN + k0;
  if (q & 1){
    if (ko < vw)     obase[ko]   = make_float2(-Bs[p2][ko],   -Bi_[p2][ko]);
    if (ko + 1 < vw) obase[ko+1] = make_float2(-Bs[p2][ko+1], -Bi_[p2][ko+1]);
  } else {
    if (ko < vw)     obase[ko]   = make_float2( As[p2][ko],    Ai_[p2][ko]);
    if (ko + 1 < vw) obase[ko+1] = make_float2( As[p2][ko+1],  Ai_[p2][ko+1]);
  }
}

// ---------------- Fat-texel build: FAT[z][y][x][8] = 2x2x2 neighborhood ------
__global__ __launch_bounds__(256) void k_fat(const float2* __restrict__ volF,
                                             float2* __restrict__ FAT){
  int idx = blockIdx.x*256 + threadIdx.x;        // over 128*128*65
  int x = idx % 65; int zy = idx / 65; int y = zy & 127; int z = zy >> 7;
  int z1 = min(z+1,127), y1 = min(y+1,127), x1 = min(x+1,64);
  const size_t s00 = ((size_t)z *128 + y )*65;
  const size_t s01 = ((size_t)z *128 + y1)*65;
  const size_t s10 = ((size_t)z1*128 + y )*65;
  const size_t s11 = ((size_t)z1*128 + y1)*65;
  float2 a0 = volF[s00+x], a1 = volF[s00+x1];
  float2 b0 = volF[s01+x], b1 = volF[s01+x1];
  float2 c0 = volF[s10+x], c1 = volF[s10+x1];
  float2 d0 = volF[s11+x], d1 = volF[s11+x1];
  float4* o = (float4*)(FAT + ((size_t)idx << 3));
  o[0] = make_float4(a0.x, a0.y, a1.x, a1.y);
  o[1] = make_float4(b0.x, b0.y, b1.x, b1.y);
  o[2] = make_float4(c0.x, c0.y, c1.x, c1.y);
  o[3] = make_float4(d0.x, d0.y, d1.x, d1.y);
}

// ---- prod element: fat-texel trilinear sample * ctf, then f * conj(P) -------
__device__ __forceinline__ float2 prod_elem(int h, int kx,
                                            float c1z, float c1y, float c1x,
                                            float c2z, float c2y, float c2x,
                                            const float2* __restrict__ FAT,
                                            const float2* __restrict__ fpc,
                                            const float*  __restrict__ cfc){
  float fyv = (float)(h - 64) * 0.0078125f;
  float fxv = (float)kx * 0.0078125f;
  float cz = fyv*c1z + fxv*c2z;
  float cy = fyv*c1y + fxv*c2y;
  float cx = fyv*c1x + fxv*c2x;
  bool cj = (cx < 0.f);
  if (cj){ cz = -cz; cy = -cy; cx = -cx; }
  float pz = cz*128.f + 64.f;
  float py = cy*128.f + 64.f;
  float px = cx*128.f;
  float fz = floorf(pz), fy = floorf(py), fx = floorf(px);
  int iz = (int)fz, iy = (int)fy, ix = (int)fx;
  float tz = pz - fz, ty = py - fy, tx = px - fx;
  float wz0 = ((unsigned)iz < 128u) ? 1.f - tz : ((iz == -1) ? tz : 0.f);
  float wz1 = ((unsigned)iz < 127u) ? tz : 0.f;
  float wy0 = ((unsigned)iy < 128u) ? 1.f - ty : ((iy == -1) ? ty : 0.f);
  float wy1 = ((unsigned)iy < 127u) ? ty : 0.f;
  float wx0 = ((unsigned)ix < 65u)  ? 1.f - tx : ((ix == -1) ? tx : 0.f);
  float wx1 = ((unsigned)ix < 64u)  ? tx : 0.f;
  int bz = min(max(iz, 0), 127), by = min(max(iy, 0), 127), bx = min(max(ix, 0), 64);
  const float4* F = (const float4*)(FAT + ((((size_t)bz*128 + by)*65 + bx) << 3));
  float4 f0 = F[0], f1 = F[1], f2 = F[2], f3 = F[3];
  float w00 = wz0*wy0, w01 = wz0*wy1, w10 = wz1*wy0, w11 = wz1*wy1;
  float ar = w00*(wx0*f0.x + wx1*f0.z) + w01*(wx0*f1.x + wx1*f1.z)
           + w10*(wx0*f2.x + wx1*f2.z) + w11*(wx0*f3.x + wx1*f3.z);
  float ai = w00*(wx0*f0.y + wx1*f0.w) + w01*(wx0*f1.y + wx1*f1.w)
           + w10*(wx0*f2.y + wx1*f2.w) + w11*(wx0*f3.y + wx1*f3.w);
  if (cj) ai = -ai;
  float ct = cfc[h];
  float Pr = ar*ct, Pi = ai*ct;
  float2 f = fpc[h];
  return make_float2(f.x*Pr + f.y*Pi, f.y*Pr - f.x*Pi);   // f * conj(P)
}

// ---------------- Main: slice + ctf + conj-mult + wave-FFT + argmax ----------
__global__ __launch_bounds__(512, 8) void k_main(const float2* __restrict__ FAT,
                                                 const float2* __restrict__ fpT,
                                                 const float* __restrict__ cfT,
                                                 const float* __restrict__ mats,
                                                 float* __restrict__ bestv,
                                                 int* __restrict__ besti){
  __shared__ float2 Q[64*65];       // Q[s][kx], normalized, window rows only
  __shared__ float rvw[8];
  __shared__ int   riw[8];

  int t = threadIdx.x, lane = t & 63, g = t >> 6;   // g = 0..7
  int blk = blockIdx.x;
  int b = blk & 7;                  // XCD-pinned batch
  int o = blk >> 3;                 // option

  float twr[7], twi[7];
  fft_twiddles(1.f, lane, twr, twi);

  const float* mp = mats + (size_t)(b*NOPT + o)*12;
  float c1z = mp[0], c1y = mp[1], c1x = mp[2];
  float c2z = mp[3], c2y = mp[4], c2x = mp[5];
  const float2* fp = fpT + (size_t)b*KXN*DIMN;
  const float*  cf = cfT + (size_t)b*KXN*DIMN;

  int e = bitrev7(lane);                         // even
  int slA = (e + 32) & 127;                      // window row for bin e
  bool inwin = (slA < 64);
  const float NRM = 6.103515625e-05f;            // 1/16384

  // ---- Phase A+B: prod columns -> FFT over h -> Q rows ----
#pragma unroll 2
  for (int ci = 0; ci < 8; ++ci){
    int kx = 8*ci + g;                           // <= 63
    const float2* fpc = fp + (size_t)kx*DIMN;
    const float*  cfc = cf + (size_t)kx*DIMN;
    float2 A = prod_elem(lane,      kx, c1z,c1y,c1x, c2z,c2y,c2x, FAT, fpc, cfc);
    float2 B = prod_elem(lane + 64, kx, c1z,c1y,c1x, c2z,c2y,c2x, FAT, fpc, cfc);
    wave_fft128(A.x, A.y, B.x, B.y, twr, twi, lane);
    if (inwin){
      Q[slA*KXN + kx]     = make_float2( A.x*NRM,  A.y*NRM);
      Q[(slA+1)*KXN + kx] = make_float2(-B.x*NRM, -B.y*NRM);
    }
  }
  if (g == 0){
    const int kx = 64;
    const float2* fpc = fp + (size_t)kx*DIMN;
    const float*  cfc = cf + (size_t)kx*DIMN;
    float2 A = prod_elem(lane,      kx, c1z,c1y,c1x, c2z,c2y,c2x, FAT, fpc, cfc);
    float2 B = prod_elem(lane + 64, kx, c1z,c1y,c1x, c2z,c2y,c2x, FAT, fpc, cfc);
    wave_fft128(A.x, A.y, B.x, B.y, twr, twi, lane);
    if (inwin){
      Q[slA*KXN + kx]     = make_float2( A.x*NRM,  A.y*NRM);
      Q[(slA+1)*KXN + kx] = make_float2(-B.x*NRM, -B.y*NRM);
    }
  }
  __syncthreads();

  // ---- Phase C: 32 row-pair FFTs over kx (Hermitian-packed), fused argmax ----
  float bv = -INFINITY; int bi = 0;
  int ra = 64 - lane;
#pragma unroll 1
  for (int pi = 0; pi < 4; ++pi){
    int r1 = (4*g + pi) << 1;
    float2 a1 = Q[r1*KXN + lane];
    float2 a2 = Q[(r1+1)*KXN + lane];
    float2 b1 = Q[r1*KXN + ra];
    float2 b2 = Q[(r1+1)*KXN + ra];
    if (lane == 0){ a1.y = 0.f; a2.y = 0.f; b1.y = 0.f; b2.y = 0.f; }
    else { b1.y = -b1.y; b2.y = -b2.y; }
    float zAr = a1.x - a2.y, zAi = a1.y + a2.x;
    float zBr = b1.x - b2.y, zBi = b1.y + b2.x;
    wave_fft128(zAr, zAi, zBr, zBi, twr, twi, lane);
    if (inwin){
      int i0 = (r1 << 6) + slA;
      if (zAr > bv || (zAr == bv && i0      < bi)){ bv = zAr; bi = i0; }
      if (zAi > bv || (zAi == bv && i0+64   < bi)){ bv = zAi; bi = i0+64; }
      if (zBr > bv || (zBr == bv && i0+1    < bi)){ bv = zBr; bi = i0+1; }
      if (zBi > bv || (zBi == bv && i0+65   < bi)){ bv = zBi; bi = i0+65; }
    }
  }

#pragma unroll
  for (int off = 32; off > 0; off >>= 1){
    float v2 = __shfl_down(bv, off, 64);
    int   i2 = __shfl_down(bi, off, 64);
    if (v2 > bv || (v2 == bv && i2 < bi)){ bv = v2; bi = i2; }
  }
  if (lane == 0){ rvw[g] = bv; riw[g] = bi; }
  __syncthreads();
  if (t == 0){
    float fv = rvw[0]; int fi = riw[0];
#pragma unroll
    for (int wv = 1; wv < 8; ++wv){
      float v2 = rvw[wv]; int i2 = riw[wv];
      if (v2 > fv || (v2 == fv && i2 < fi)){ fv = v2; fi = i2; }
    }
    bestv[b*NOPT + o] = fv; besti[b*NOPT + o] = fi;
  }
}

// ---------------- Final selection / outputs ----------------------------------
__global__ __launch_bounds__(64) void k_out(const float* __restrict__ bestv,
                                            const int* __restrict__ besti,
                                            const float* __restrict__ mats,
                                            float* __restrict__ out){
  int b = blockIdx.x;
  if (threadIdx.x != 0) return;
  float bv = -INFINITY; int bo = 0;
  for (int o = 0; o < NOPT; ++o){
    float v = bestv[b*NOPT + o];
    if (v > bv){ bv = v; bo = o; }
  }
  float sum = 0.f;
  for (int o = 0; o < NOPT; ++o) sum += bestv[b*NOPT + o];
  float mean = sum * (1.0f/125.0f);
  float ss = 0.f;
  for (int o = 0; o < NOPT; ++o){
    float d = bestv[b*NOPT + o] - mean;
    ss += d*d;
  }
  float stdv = sqrtf(ss * (1.0f/124.0f));

  int wi = besti[b*NOPT + bo];
  int row = (wi >> 6) + 32;
  int col = (wi & 63) + 32;

  out[b] = bv;
  const float* mm = mats + (size_t)(b*NOPT + bo)*12;
  const float RAD = 0.017453292519943295f;
  float sa, ca, sb, cb, sc, cc;
  sincosf(mm[6]*RAD, &sa, &ca);
  sincosf(mm[7]*RAD, &sb, &cb);
  sincosf(mm[8]*RAD, &sc, &cc);
  float* R = out + 8 + b*9;
  R[0] = ca*cb*cc - sa*sc;  R[1] = -ca*cb*sc - sa*cc;  R[2] = ca*sb;
  R[3] = sa*cb*cc + ca*sc;  R[4] = -sa*cb*sc + ca*cc;  R[5] = sa*sb;
  R[6] = -sb*cc;            R[7] = sb*sc;              R[8] = cb;
  out[80 + b*2 + 0] = -((float)col - 64.f) * 1.5f;
  out[80 + b*2 + 1] = -((float)row - 64.f) * 1.5f;
  float z = (bv - mean) / ((stdv + 1e-6f) * 1.4142135623730951f);
  out[96 + b] = 0.5f*(1.f + erff(z));
}

extern "C" void kernel_launch(void* const* d_in, const int* in_sizes, int n_in,
                              void* d_out, int out_size, void* d_ws, size_t ws_size,
                              hipStream_t stream){
  (void)in_sizes; (void)n_in; (void)out_size; (void)ws_size;
  const float* vol  = (const float*)d_in[0];
  const float* imgs = (const float*)d_in[1];
  const float* ctfs = (const float*)d_in[2];
  const float* rotm = (const float*)d_in[3];
  float* out = (float*)d_out;

  float2* FAT   = (float2*)d_ws;                        // 128*128*65*8 cplx = 68 MB
  float2* bufA  = FAT  + ((size_t)DIMN*DIMN*KXN*8);     // 128*128*65 cplx
  float2* bufB  = bufA + (size_t)DIMN*DIMN*KXN;         // 128*128*65 cplx
  float2* imgT  = bufB + (size_t)DIMN*DIMN*KXN;         // 8*65*128 cplx
  float2* fpT   = imgT + (size_t)NBATCH*KXN*DIMN;       // 8*65*128 cplx
  float*  cfT   = (float*)(fpT + (size_t)NBATCH*KXN*DIMN);   // 8*65*128 f32
  float*  mats  = cfT + (size_t)NBATCH*KXN*DIMN;        // 1000*12 f32
  float*  bestv = mats + 12000;                         // 1000 f32
  int*    besti = (int*)(bestv + 1000);                 // 1000 i32

  k_pre1<<<2440, 256, 0, stream>>>(vol, imgs, ctfs, rotm, bufA, imgT, cfT, mats);
  k_pre2<<<1105, 512, 0, stream>>>(bufA, imgT, bufB, fpT);
  k_fz<<<1152, 512, 0, stream>>>(bufB, bufA);           // bufA == vol_rfft
  k_fat<<<(DIMN*DIMN*KXN)/256, 256, 0, stream>>>(bufA, FAT);
  k_main<<<NBATCH*NOPT, 512, 0, stream>>>(FAT, fpT, cfT, mats, bestv, besti);
  k_out<<<NBATCH, 64, 0, stream>>>(bestv, besti, mats, out);
}

// Round 8
// 114.772 us; speedup vs baseline: 3.6749x; 1.4309x over previous
//
#include <hip/hip_runtime.h>
#include <hip/hip_fp16.h>
#include <math.h>

#define DIMN 128
#define KXN  65
#define NBATCH 8
#define NOPT 125

// ============ wave-level 128-point FFT (radix-2 DIF, 2 points/lane) ==========
__device__ __forceinline__ void fft_twiddles(float sigma, int lane,
                                             float* twr, float* twi){
  const float W = 0.04908738521234052f;   // 2*pi/128
  float s, c;
  sincosf(sigma * W * (float)lane, &s, &c);
  twr[0] = c; twi[0] = s;
#pragma unroll
  for (int st = 1; st <= 6; ++st){
    int off = 64 >> st;
    int m = (lane & (off - 1)) << st;
    sincosf(sigma * W * (float)m, &s, &c);
    bool hi = (lane & off) != 0;
    twr[st] = hi ? c : 1.f;
    twi[st] = hi ? s : 0.f;
  }
}

__device__ __forceinline__ void wave_fft128(float& Ar, float& Ai, float& Br, float& Bi,
                                            const float* twr, const float* twi, int lane){
  {
    float dr = Ar - Br, di = Ai - Bi;
    Ar += Br; Ai += Bi;
    float nr = dr*twr[0] - di*twi[0];
    Bi = dr*twi[0] + di*twr[0];
    Br = nr;
  }
#pragma unroll
  for (int s = 1; s <= 6; ++s){
    int off = 64 >> s;
    float sgn = (lane & off) ? -1.f : 1.f;
    float pr = __shfl_xor(Ar, off, 64);
    float pi = __shfl_xor(Ai, off, 64);
    float dr = fmaf(Ar, sgn, pr);
    float di = fmaf(Ai, sgn, pi);
    Ar = dr*twr[s] - di*twi[s];
    Ai = dr*twi[s] + di*twr[s];
    pr = __shfl_xor(Br, off, 64);
    pi = __shfl_xor(Bi, off, 64);
    dr = fmaf(Br, sgn, pr);
    di = fmaf(Bi, sgn, pi);
    Br = dr*twr[s] - di*twi[s];
    Bi = dr*twi[s] + di*twr[s];
  }
}

__device__ __forceinline__ int bitrev7(int lane){
  return (int)(__brev((unsigned)lane) >> 25);
}

__device__ __forceinline__ float2 h2f2(unsigned u){
  union { unsigned u; __half2 h; } cv; cv.u = u;
  return __half22float2(cv.h);
}
__device__ __forceinline__ unsigned f2h2(float re, float im){
  union { unsigned u; __half2 h; } cv;
  cv.h = __float22half2_rn(make_float2(re, im));
  return cv.u;
}

// ======================= Launch 1: fx passes + ctfT + mats ===================
__global__ __launch_bounds__(256) void k_pre1(const float* __restrict__ vol,
                                              const float* __restrict__ imgs,
                                              const float* __restrict__ ctfs,
                                              const float* __restrict__ rotm,
                                              float2* __restrict__ A_T,
                                              float2* __restrict__ AI_T,
                                              float* __restrict__ cfT,
                                              float* __restrict__ mats){
  __shared__ float2 Zbuf[4][128];
  __shared__ float Xr[65][9];
  __shared__ float Xi[65][9];
  int bid = blockIdx.x;
  int t = threadIdx.x, lane = t & 63, w = t >> 6;

  if (bid < 2176){
    bool isimg = (bid >= 2048);
    const float* src = isimg ? imgs : vol;
    float2* dst = isimg ? AI_T : A_T;
    int l0 = (isimg ? (bid - 2048) : bid) * 8;
    int l1 = l0 + 2*w, l2 = l1 + 1;
    float m1a = 1.f, m1b = 1.f, m2a = 1.f, m2b = 1.f;
    if (isimg){
      int y1 = l1 & 127, y2 = y1 + 1;
      int dy1 = y1 - 64, dy2 = y2 - 64;
      int dxa = lane - 64, dxb = lane;
      m1a = (dy1*dy1 + dxa*dxa <= 4096) ? 1.f : 0.f;
      m1b = (dy1*dy1 + dxb*dxb <= 4096) ? 1.f : 0.f;
      m2a = (dy2*dy2 + dxa*dxa <= 4096) ? 1.f : 0.f;
      m2b = (dy2*dy2 + dxb*dxb <= 4096) ? 1.f : 0.f;
    }
    float twr[7], twi[7];
    fft_twiddles(-1.f, lane, twr, twi);
    float Ar = src[l1*DIMN + lane]*m1a,      Ai = src[l2*DIMN + lane]*m2a;
    float Br = src[l1*DIMN + lane + 64]*m1b, Bi = src[l2*DIMN + lane + 64]*m2b;
    wave_fft128(Ar, Ai, Br, Bi, twr, twi, lane);
    int e = bitrev7(lane);
    Zbuf[w][e]   = make_float2(Ar, Ai);
    Zbuf[w][e+1] = make_float2(Br, Bi);
    __syncthreads();
    {
      int k = lane, m = (128 - k) & 127;
      float2 zk = Zbuf[w][k], zm = Zbuf[w][m];
      float s = (k & 1) ? -0.5f : 0.5f;
      int ly1 = 2*w, ly2 = ly1 + 1;
      Xr[k][ly1] = s*(zk.x + zm.x);  Xi[k][ly1] = s*(zk.y - zm.y);
      Xr[k][ly2] = s*(zk.y + zm.y);  Xi[k][ly2] = s*(zm.x - zk.x);
      if (lane == 0){
        float2 z64 = Zbuf[w][64];
        Xr[64][ly1] = z64.x; Xi[64][ly1] = 0.f;
        Xr[64][ly2] = z64.y; Xi[64][ly2] = 0.f;
      }
    }
    __syncthreads();
    int slab = l0 >> 7, y0 = l0 & 127;
    int kk = t >> 2, yo = (t & 3) * 2;
    float4 v = make_float4(Xr[kk][yo], Xi[kk][yo], Xr[kk][yo+1], Xi[kk][yo+1]);
    *(float4*)(dst + (size_t)(slab*KXN + kk)*DIMN + y0 + yo) = v;
    if (t < 4){
      int yo2 = t*2;
      float4 v2 = make_float4(Xr[64][yo2], Xi[64][yo2], Xr[64][yo2+1], Xi[64][yo2+1]);
      *(float4*)(dst + (size_t)(slab*KXN + 64)*DIMN + y0 + yo2) = v2;
    }
  } else if (bid < 2436){
    int idx = (bid - 2176)*256 + t;
    int x = idx % 65; int by = idx / 65; int y = by & 127; int b = by >> 7;
    cfT[((size_t)b*KXN + x)*DIMN + y] = ctfs[idx];
  } else {
    int tid = (bid - 2436)*256 + t;
    if (tid < NBATCH*NOPT){
      int b = tid / NOPT, o = tid - b*NOPT;
      const float* R = rotm + b*9;
      float beta  = acosf(fminf(1.f, fmaxf(-1.f, R[8])));
      float alpha = atan2f(R[5], R[2]);
      float gamma = atan2f(R[7], -R[6]);
      const float DEG = 57.29577951308232f;
      float e0 = alpha*DEG + 3.0f*(float)(o/25      - 2);
      float e1 = beta *DEG + 3.0f*(float)((o/5) % 5 - 2);
      float e2 = gamma*DEG + 3.0f*(float)(o % 5     - 2);
      const float RAD = 0.017453292519943295f;
      float sa, ca, sb, cb, sc, cc;
      sincosf(e0*RAD, &sa, &ca);
      sincosf(e1*RAD, &sb, &cb);
      sincosf(e2*RAD, &sc, &cc);
      float* m = mats + tid*12;
      m[0] = sb*sc;
      m[1] = -sa*cb*sc + ca*cc;
      m[2] = -ca*cb*sc - sa*cc;
      m[3] = -sb*cc;
      m[4] = sa*cb*cc + ca*sc;
      m[5] = ca*cb*cc - sa*sc;
      m[6] = e0; m[7] = e1; m[8] = e2;
    }
  }
}

// ======================= Launch 2: fy passes (vol + img) =====================
__global__ __launch_bounds__(512) void k_pre2(const float2* __restrict__ A_T,
                                              const float2* __restrict__ AI_T,
                                              float2* __restrict__ B_T,
                                              float2* __restrict__ fpT){
  __shared__ float As[64][9], Ai_[64][9], Bs[64][9], Bi_[64][9];
  int bid = blockIdx.x;
  int t = threadIdx.x, lane = t & 63, w = t >> 6;
  float twr[7], twi[7];
  fft_twiddles(-1.f, lane, twr, twi);

  if (bid < 1040){
    int k = bid >> 4, z0 = (bid & 15) * 8;
    int col = (z0 + w)*KXN + k;
    const float2* base = A_T + (size_t)col*DIMN;
    float2 A = base[lane], B = base[lane + 64];
    wave_fft128(A.x, A.y, B.x, B.y, twr, twi, lane);
    int p = bitrev7(lane) >> 1;
    As[p][w] = A.x; Ai_[p][w] = A.y; Bs[p][w] = B.x; Bi_[p][w] = B.y;
    __syncthreads();
    int q = t >> 2, zo = (t & 3) * 2;
    int p2 = (((q & 126) + 64) & 127) >> 1;
    float4 v;
    if (q & 1) v = make_float4(-Bs[p2][zo], -Bi_[p2][zo], -Bs[p2][zo+1], -Bi_[p2][zo+1]);
    else       v = make_float4( As[p2][zo],  Ai_[p2][zo],  As[p2][zo+1],  Ai_[p2][zo+1]);
    *(float4*)(B_T + (size_t)(q*KXN + k)*DIMN + z0 + zo) = v;
  } else {
    int c0 = (bid - 1040) * 8;
    int col = c0 + w;
    const float2* base = AI_T + (size_t)col*DIMN;
    float2 A = base[lane], B = base[lane + 64];
    wave_fft128(A.x, A.y, B.x, B.y, twr, twi, lane);
    int p = bitrev7(lane) >> 1;
    As[p][w] = A.x; Ai_[p][w] = A.y; Bs[p][w] = B.x; Bi_[p][w] = B.y;
    __syncthreads();
    int c = t >> 6, qo = (t & 63) * 2;
    int p2 = ((qo + 64) & 127) >> 1;
    float4 v = make_float4(As[p2][c], Ai_[p2][c], -Bs[p2][c], -Bi_[p2][c]);
    *(float4*)(fpT + (size_t)(c0 + c)*DIMN + qo) = v;
  }
}

// ======================= Launch 3: vol fz pass ===============================
__global__ __launch_bounds__(512) void k_fz(const float2* __restrict__ B_T,
                                            float2* __restrict__ volF){
  __shared__ float As[64][9], Ai_[64][9], Bs[64][9], Bi_[64][9];
  int bid = blockIdx.x;
  int j = bid / 9, grp = bid - j*9;
  int k0 = grp * 8;
  int vw = (grp == 8) ? 1 : 8;
  int t = threadIdx.x, lane = t & 63, w = t >> 6;
  if (w < vw){
    float twr[7], twi[7];
    fft_twiddles(-1.f, lane, twr, twi);
    int col = j*KXN + k0 + w;
    const float2* base = B_T + (size_t)col*DIMN;
    float2 A = base[lane], B = base[lane + 64];
    wave_fft128(A.x, A.y, B.x, B.y, twr, twi, lane);
    int p = bitrev7(lane) >> 1;
    As[p][w] = A.x; Ai_[p][w] = A.y; Bs[p][w] = B.x; Bi_[p][w] = B.y;
  }
  __syncthreads();
  int q = t >> 2, ko = (t & 3) * 2;
  int p2 = (((q & 126) + 64) & 127) >> 1;
  float2* obase = volF + (size_t)(q*DIMN + j)*KXN + k0;
  if (q & 1){
    if (ko < vw)     obase[ko]   = make_float2(-Bs[p2][ko],   -Bi_[p2][ko]);
    if (ko + 1 < vw) obase[ko+1] = make_float2(-Bs[p2][ko+1], -Bi_[p2][ko+1]);
  } else {
    if (ko < vw)     obase[ko]   = make_float2( As[p2][ko],    Ai_[p2][ko]);
    if (ko + 1 < vw) obase[ko+1] = make_float2( As[p2][ko+1],  Ai_[p2][ko+1]);
  }
}

// ---------------- Fat-texel build (fp16): FATh[idx][8] half2 = 32 B ----------
// order: v000,v001,v010,v011,v100,v101,v110,v111 (y then x inner, z outer)
__global__ __launch_bounds__(256) void k_fat(const float2* __restrict__ volF,
                                             unsigned* __restrict__ FATh){
  int idx = blockIdx.x*256 + threadIdx.x;        // over 128*128*65
  int x = idx % 65; int zy = idx / 65; int y = zy & 127; int z = zy >> 7;
  int z1 = min(z+1,127), y1 = min(y+1,127), x1 = min(x+1,64);
  const size_t s00 = ((size_t)z *128 + y )*65;
  const size_t s01 = ((size_t)z *128 + y1)*65;
  const size_t s10 = ((size_t)z1*128 + y )*65;
  const size_t s11 = ((size_t)z1*128 + y1)*65;
  float2 a0 = volF[s00+x], a1 = volF[s00+x1];
  float2 b0 = volF[s01+x], b1 = volF[s01+x1];
  float2 c0 = volF[s10+x], c1 = volF[s10+x1];
  float2 d0 = volF[s11+x], d1 = volF[s11+x1];
  uint4* o = (uint4*)(FATh + ((size_t)idx << 3));
  o[0] = make_uint4(f2h2(a0.x,a0.y), f2h2(a1.x,a1.y), f2h2(b0.x,b0.y), f2h2(b1.x,b1.y));
  o[1] = make_uint4(f2h2(c0.x,c0.y), f2h2(c1.x,c1.y), f2h2(d0.x,d0.y), f2h2(d1.x,d1.y));
}

// ---- prod element: fp16 fat-texel trilinear sample * ctf, then f * conj(P) --
__device__ __forceinline__ float2 prod_elem(int h, int kx,
                                            float c1z, float c1y, float c1x,
                                            float c2z, float c2y, float c2x,
                                            const unsigned* __restrict__ FATh,
                                            const float2* __restrict__ fpc,
                                            const float*  __restrict__ cfc){
  float fyv = (float)(h - 64) * 0.0078125f;
  float fxv = (float)kx * 0.0078125f;
  float cz = fyv*c1z + fxv*c2z;
  float cy = fyv*c1y + fxv*c2y;
  float cx = fyv*c1x + fxv*c2x;
  bool cj = (cx < 0.f);
  if (cj){ cz = -cz; cy = -cy; cx = -cx; }
  float pz = cz*128.f + 64.f;
  float py = cy*128.f + 64.f;
  float px = cx*128.f;
  float fz = floorf(pz), fy = floorf(py), fx = floorf(px);
  int iz = (int)fz, iy = (int)fy, ix = (int)fx;
  float tz = pz - fz, ty = py - fy, tx = px - fx;
  float wz0 = ((unsigned)iz < 128u) ? 1.f - tz : ((iz == -1) ? tz : 0.f);
  float wz1 = ((unsigned)iz < 127u) ? tz : 0.f;
  float wy0 = ((unsigned)iy < 128u) ? 1.f - ty : ((iy == -1) ? ty : 0.f);
  float wy1 = ((unsigned)iy < 127u) ? ty : 0.f;
  float wx0 = ((unsigned)ix < 65u)  ? 1.f - tx : ((ix == -1) ? tx : 0.f);
  float wx1 = ((unsigned)ix < 64u)  ? tx : 0.f;
  int bz = min(max(iz, 0), 127), by = min(max(iy, 0), 127), bx = min(max(ix, 0), 64);
  const uint4* F = (const uint4*)(FATh + ((((size_t)bz*128 + by)*65 + bx) << 3));
  uint4 u0 = F[0], u1 = F[1];
  float2 v000 = h2f2(u0.x), v001 = h2f2(u0.y), v010 = h2f2(u0.z), v011 = h2f2(u0.w);
  float2 v100 = h2f2(u1.x), v101 = h2f2(u1.y), v110 = h2f2(u1.z), v111 = h2f2(u1.w);
  float w00 = wz0*wy0, w01 = wz0*wy1, w10 = wz1*wy0, w11 = wz1*wy1;
  float ar = w00*(wx0*v000.x + wx1*v001.x) + w01*(wx0*v010.x + wx1*v011.x)
           + w10*(wx0*v100.x + wx1*v101.x) + w11*(wx0*v110.x + wx1*v111.x);
  float ai = w00*(wx0*v000.y + wx1*v001.y) + w01*(wx0*v010.y + wx1*v011.y)
           + w10*(wx0*v100.y + wx1*v101.y) + w11*(wx0*v110.y + wx1*v111.y);
  if (cj) ai = -ai;
  float ct = cfc[h];
  float Pr = ar*ct, Pi = ai*ct;
  float2 f = fpc[h];
  return make_float2(f.x*Pr + f.y*Pi, f.y*Pr - f.x*Pi);   // f * conj(P)
}

// ---------------- Main: slice + ctf + conj-mult + wave-FFT + argmax ----------
__global__ __launch_bounds__(512, 8) void k_main(const unsigned* __restrict__ FATh,
                                                 const float2* __restrict__ fpT,
                                                 const float* __restrict__ cfT,
                                                 const float* __restrict__ mats,
                                                 float* __restrict__ bestv,
                                                 int* __restrict__ besti){
  __shared__ float2 Q[64*65];       // Q[s][kx], normalized, window rows only
  __shared__ float rvw[8];
  __shared__ int   riw[8];

  int t = threadIdx.x, lane = t & 63, g = t >> 6;   // g = 0..7
  int blk = blockIdx.x;
  int b = blk & 7;                  // XCD-pinned batch
  int o = blk >> 3;                 // option

  float twr[7], twi[7];
  fft_twiddles(1.f, lane, twr, twi);

  const float* mp = mats + (size_t)(b*NOPT + o)*12;
  float c1z = mp[0], c1y = mp[1], c1x = mp[2];
  float c2z = mp[3], c2y = mp[4], c2x = mp[5];
  const float2* fp = fpT + (size_t)b*KXN*DIMN;
  const float*  cf = cfT + (size_t)b*KXN*DIMN;

  int e = bitrev7(lane);                         // even
  int slA = (e + 32) & 127;                      // window row for bin e
  bool inwin = (slA < 64);
  const float NRM = 6.103515625e-05f;            // 1/16384

  // ---- Phase A+B: prod columns -> FFT over h -> Q rows ----
#pragma unroll 1
  for (int ci = 0; ci < 8; ++ci){
    int kx = 8*ci + g;                           // <= 63
    const float2* fpc = fp + (size_t)kx*DIMN;
    const float*  cfc = cf + (size_t)kx*DIMN;
    float2 A = prod_elem(lane,      kx, c1z,c1y,c1x, c2z,c2y,c2x, FATh, fpc, cfc);
    float2 B = prod_elem(lane + 64, kx, c1z,c1y,c1x, c2z,c2y,c2x, FATh, fpc, cfc);
    wave_fft128(A.x, A.y, B.x, B.y, twr, twi, lane);
    if (inwin){
      Q[slA*KXN + kx]     = make_float2( A.x*NRM,  A.y*NRM);
      Q[(slA+1)*KXN + kx] = make_float2(-B.x*NRM, -B.y*NRM);
    }
  }
  if (g == 0){
    const int kx = 64;
    const float2* fpc = fp + (size_t)kx*DIMN;
    const float*  cfc = cf + (size_t)kx*DIMN;
    float2 A = prod_elem(lane,      kx, c1z,c1y,c1x, c2z,c2y,c2x, FATh, fpc, cfc);
    float2 B = prod_elem(lane + 64, kx, c1z,c1y,c1x, c2z,c2y,c2x, FATh, fpc, cfc);
    wave_fft128(A.x, A.y, B.x, B.y, twr, twi, lane);
    if (inwin){
      Q[slA*KXN + kx]     = make_float2( A.x*NRM,  A.y*NRM);
      Q[(slA+1)*KXN + kx] = make_float2(-B.x*NRM, -B.y*NRM);
    }
  }
  __syncthreads();

  // ---- Phase C: 32 row-pair FFTs over kx (Hermitian-packed), fused argmax ----
  float bv = -INFINITY; int bi = 0;
  int ra = 64 - lane;
#pragma unroll 1
  for (int pi = 0; pi < 4; ++pi){
    int r1 = (4*g + pi) << 1;
    float2 a1 = Q[r1*KXN + lane];
    float2 a2 = Q[(r1+1)*KXN + lane];
    float2 b1 = Q[r1*KXN + ra];
    float2 b2 = Q[(r1+1)*KXN + ra];
    if (lane == 0){ a1.y = 0.f; a2.y = 0.f; b1.y = 0.f; b2.y = 0.f; }
    else { b1.y = -b1.y; b2.y = -b2.y; }
    float zAr = a1.x - a2.y, zAi = a1.y + a2.x;
    float zBr = b1.x - b2.y, zBi = b1.y + b2.x;
    wave_fft128(zAr, zAi, zBr, zBi, twr, twi, lane);
    if (inwin){
      int i0 = (r1 << 6) + slA;
      if (zAr > bv || (zAr == bv && i0      < bi)){ bv = zAr; bi = i0; }
      if (zAi > bv || (zAi == bv && i0+64   < bi)){ bv = zAi; bi = i0+64; }
      if (zBr > bv || (zBr == bv && i0+1    < bi)){ bv = zBr; bi = i0+1; }
      if (zBi > bv || (zBi == bv && i0+65   < bi)){ bv = zBi; bi = i0+65; }
    }
  }

#pragma unroll
  for (int off = 32; off > 0; off >>= 1){
    float v2 = __shfl_down(bv, off, 64);
    int   i2 = __shfl_down(bi, off, 64);
    if (v2 > bv || (v2 == bv && i2 < bi)){ bv = v2; bi = i2; }
  }
  if (lane == 0){ rvw[g] = bv; riw[g] = bi; }
  __syncthreads();
  if (t == 0){
    float fv = rvw[0]; int fi = riw[0];
#pragma unroll
    for (int wv = 1; wv < 8; ++wv){
      float v2 = rvw[wv]; int i2 = riw[wv];
      if (v2 > fv || (v2 == fv && i2 < fi)){ fv = v2; fi = i2; }
    }
    bestv[b*NOPT + o] = fv; besti[b*NOPT + o] = fi;
  }
}

// ---------------- Final selection / outputs ----------------------------------
__global__ __launch_bounds__(64) void k_out(const float* __restrict__ bestv,
                                            const int* __restrict__ besti,
                                            const float* __restrict__ mats,
                                            float* __restrict__ out){
  int b = blockIdx.x;
  if (threadIdx.x != 0) return;
  float bv = -INFINITY; int bo = 0;
  for (int o = 0; o < NOPT; ++o){
    float v = bestv[b*NOPT + o];
    if (v > bv){ bv = v; bo = o; }
  }
  float sum = 0.f;
  for (int o = 0; o < NOPT; ++o) sum += bestv[b*NOPT + o];
  float mean = sum * (1.0f/125.0f);
  float ss = 0.f;
  for (int o = 0; o < NOPT; ++o){
    float d = bestv[b*NOPT + o] - mean;
    ss += d*d;
  }
  float stdv = sqrtf(ss * (1.0f/124.0f));

  int wi = besti[b*NOPT + bo];
  int row = (wi >> 6) + 32;
  int col = (wi & 63) + 32;

  out[b] = bv;
  const float* mm = mats + (size_t)(b*NOPT + bo)*12;
  const float RAD = 0.017453292519943295f;
  float sa, ca, sb, cb, sc, cc;
  sincosf(mm[6]*RAD, &sa, &ca);
  sincosf(mm[7]*RAD, &sb, &cb);
  sincosf(mm[8]*RAD, &sc, &cc);
  float* R = out + 8 + b*9;
  R[0] = ca*cb*cc - sa*sc;  R[1] = -ca*cb*sc - sa*cc;  R[2] = ca*sb;
  R[3] = sa*cb*cc + ca*sc;  R[4] = -sa*cb*sc + ca*cc;  R[5] = sa*sb;
  R[6] = -sb*cc;            R[7] = sb*sc;              R[8] = cb;
  out[80 + b*2 + 0] = -((float)col - 64.f) * 1.5f;
  out[80 + b*2 + 1] = -((float)row - 64.f) * 1.5f;
  float z = (bv - mean) / ((stdv + 1e-6f) * 1.4142135623730951f);
  out[96 + b] = 0.5f*(1.f + erff(z));
}

extern "C" void kernel_launch(void* const* d_in, const int* in_sizes, int n_in,
                              void* d_out, int out_size, void* d_ws, size_t ws_size,
                              hipStream_t stream){
  (void)in_sizes; (void)n_in; (void)out_size; (void)ws_size;
  const float* vol  = (const float*)d_in[0];
  const float* imgs = (const float*)d_in[1];
  const float* ctfs = (const float*)d_in[2];
  const float* rotm = (const float*)d_in[3];
  float* out = (float*)d_out;

  unsigned* FATh = (unsigned*)d_ws;                     // 128*128*65*8 half2 = 34 MB
  float2* bufA  = (float2*)(FATh + ((size_t)DIMN*DIMN*KXN*8));
  float2* bufB  = bufA + (size_t)DIMN*DIMN*KXN;         // 128*128*65 cplx
  float2* imgT  = bufB + (size_t)DIMN*DIMN*KXN;         // 8*65*128 cplx
  float2* fpT   = imgT + (size_t)NBATCH*KXN*DIMN;       // 8*65*128 cplx
  float*  cfT   = (float*)(fpT + (size_t)NBATCH*KXN*DIMN);   // 8*65*128 f32
  float*  mats  = cfT + (size_t)NBATCH*KXN*DIMN;        // 1000*12 f32
  float*  bestv = mats + 12000;                         // 1000 f32
  int*    besti = (int*)(bestv + 1000);                 // 1000 i32

  k_pre1<<<2440, 256, 0, stream>>>(vol, imgs, ctfs, rotm, bufA, imgT, cfT, mats);
  k_pre2<<<1105, 512, 0, stream>>>(bufA, imgT, bufB, fpT);
  k_fz<<<1152, 512, 0, stream>>>(bufB, bufA);           // bufA == vol_rfft
  k_fat<<<(DIMN*DIMN*KXN)/256, 256, 0, stream>>>(bufA, FATh);
  k_main<<<NBATCH*NOPT, 512, 0, stream>>>(FATh, fpT, cfT, mats, bestv, besti);
  k_out<<<NBATCH, 64, 0, stream>>>(bestv, besti, mats, out);
}